// Round 1
// baseline (314.704 us; speedup 1.0000x reference)
//
#include <hip/hip_runtime.h>
#include <hip/hip_bf16.h>
#include <cstddef>

// Problem constants (B=2, L=4096, C=512, H=8, K=64, D=64)
// max_window = 12, half_max = 6, S = 13, max_offset = 12.0, hid = 128

// ---------------------------------------------------------------------------
// GEMM: C[m,n] = sum_k A[m,k] * W[n,k]  (NT, both row-major along K=512)
// 128x128 tile, BK=32, 256 threads, 8x8 microtile.
// MODE 0: dual output (n<512 -> Ck + bk ; n>=512 -> Cv + bv), no activation
// MODE 1: A scaled per-column by colscale[(m>>12)*512 + k], silu output -> Ck
// ---------------------------------------------------------------------------
template<int MODE>
__global__ __launch_bounds__(256) void gemm_nt(
    const float* __restrict__ A,
    const float* __restrict__ Wk, const float* __restrict__ Wv,
    const float* __restrict__ bk, const float* __restrict__ bv,
    float* __restrict__ Ck, float* __restrict__ Cv,
    const float* __restrict__ colscale)
{
  constexpr int K = 512;
  __shared__ float As[32][132];
  __shared__ float Ws[32][132];
  const int t  = threadIdx.x;
  const int m0 = blockIdx.x * 128;
  const int n0 = blockIdx.y * 128;
  const int tr = t >> 4, tc = t & 15;
  const int lr = t >> 1;            // tile row this thread loads (0..127)
  const int lk = (t & 1) * 16;      // k offset within BK (0 or 16)

  float acc[8][8];
#pragma unroll
  for (int i = 0; i < 8; i++)
#pragma unroll
    for (int j = 0; j < 8; j++) acc[i][j] = 0.f;

  const float* wsrc;
  {
    int n = n0 + lr;
    if (MODE == 0) wsrc = (n < 512) ? (Wk + (size_t)n * K) : (Wv + (size_t)(n - 512) * K);
    else           wsrc = Wk + (size_t)n * K;
  }
  const float* asrc  = A + (size_t)(m0 + lr) * K;
  const float* csrow = (MODE == 1) ? (colscale + (size_t)((m0 + lr) >> 12) * 512) : nullptr;

  for (int k0 = 0; k0 < K; k0 += 32) {
    float4 av[4], wv4[4];
#pragma unroll
    for (int i = 0; i < 4; i++) av[i]  = *(const float4*)(asrc + k0 + lk + i * 4);
#pragma unroll
    for (int i = 0; i < 4; i++) wv4[i] = *(const float4*)(wsrc + k0 + lk + i * 4);
    if (MODE == 1) {
#pragma unroll
      for (int i = 0; i < 4; i++) {
        const float* cs = csrow + k0 + lk + i * 4;
        av[i].x *= cs[0]; av[i].y *= cs[1]; av[i].z *= cs[2]; av[i].w *= cs[3];
      }
    }
    __syncthreads();   // previous iteration's LDS reads complete
#pragma unroll
    for (int i = 0; i < 4; i++) {
      As[lk + i * 4 + 0][lr] = av[i].x;
      As[lk + i * 4 + 1][lr] = av[i].y;
      As[lk + i * 4 + 2][lr] = av[i].z;
      As[lk + i * 4 + 3][lr] = av[i].w;
      Ws[lk + i * 4 + 0][lr] = wv4[i].x;
      Ws[lk + i * 4 + 1][lr] = wv4[i].y;
      Ws[lk + i * 4 + 2][lr] = wv4[i].z;
      Ws[lk + i * 4 + 3][lr] = wv4[i].w;
    }
    __syncthreads();
#pragma unroll
    for (int kk = 0; kk < 32; kk++) {
      float4 a0 = *(const float4*)&As[kk][tr * 8];
      float4 a1 = *(const float4*)&As[kk][tr * 8 + 4];
      float4 w0 = *(const float4*)&Ws[kk][tc * 8];
      float4 w1 = *(const float4*)&Ws[kk][tc * 8 + 4];
      float a[8] = {a0.x, a0.y, a0.z, a0.w, a1.x, a1.y, a1.z, a1.w};
      float w[8] = {w0.x, w0.y, w0.z, w0.w, w1.x, w1.y, w1.z, w1.w};
#pragma unroll
      for (int i = 0; i < 8; i++)
#pragma unroll
        for (int j = 0; j < 8; j++)
          acc[i][j] = fmaf(a[i], w[j], acc[i][j]);
    }
  }

#pragma unroll
  for (int i = 0; i < 8; i++) {
    int m = m0 + tr * 8 + i;
#pragma unroll
    for (int j = 0; j < 8; j++) {
      int n = n0 + tc * 8 + j;
      float val = acc[i][j];
      if (MODE == 0) {
        if (n < 512) Ck[(size_t)m * 512 + n]         = val + bk[n];
        else         Cv[(size_t)m * 512 + (n - 512)] = val + bv[n - 512];
      } else {
        Ck[(size_t)m * 512 + n] = val / (1.f + expf(-val));
      }
    }
  }
}

// ---------------------------------------------------------------------------
// window / offset projection (N=16 skinny) + rmsnorm(H=8) + sigmoid/tanh
// wave per row; weights staged in LDS; 16 rows per block
// ---------------------------------------------------------------------------
__global__ __launch_bounds__(256) void winoff_kernel(
    const float* __restrict__ x,
    const float* __restrict__ window_w, const float* __restrict__ window_b,
    const float* __restrict__ window_g,
    const float* __restrict__ offset_w, const float* __restrict__ offset_b,
    const float* __restrict__ offset_g,
    float* __restrict__ halfwin, float* __restrict__ cenoff)
{
  __shared__ float wsm[16][512];   // rows 0..7 window_w, 8..15 offset_w
  const int t = threadIdx.x;
  {
    float4* dst = (float4*)&wsm[0][0];
    for (int i = t; i < 2048; i += 256)
      dst[i] = (i < 1024) ? ((const float4*)window_w)[i] : ((const float4*)offset_w)[i - 1024];
  }
  __syncthreads();
  const int wid = t >> 6, lane = t & 63;
  for (int it = 0; it < 4; it++) {
    const int row = blockIdx.x * 16 + it * 4 + wid;
    const float* xr = x + (size_t)row * 512;
    float xv[8];
#pragma unroll
    for (int j = 0; j < 8; j++) xv[j] = xr[lane + j * 64];
    float s[16];
#pragma unroll
    for (int n = 0; n < 16; n++) {
      float p = 0.f;
#pragma unroll
      for (int j = 0; j < 8; j++) p += xv[j] * wsm[n][lane + j * 64];
#pragma unroll
      for (int off = 32; off >= 1; off >>= 1) p += __shfl_xor(p, off);
      s[n] = p;
    }
    float ssw = 0.f, sso = 0.f;
#pragma unroll
    for (int h = 0; h < 8; h++) {
      s[h]     += window_b[h]; ssw += s[h] * s[h];
      s[8 + h] += offset_b[h]; sso += s[8 + h] * s[8 + h];
    }
    float rw = rsqrtf(ssw * 0.125f + 1e-6f);
    float ro = rsqrtf(sso * 0.125f + 1e-6f);
    if (lane < 8) {
      float z  = window_g[lane] * s[lane] * rw;
      float wr = 1.f / (1.f + expf(-z));
      halfwin[(size_t)row * 8 + lane] = fmaxf((1.0f + wr * 11.0f) * 0.5f, 0.5f);
    } else if (lane < 16) {
      int h = lane - 8;
      float z = offset_g[h] * s[8 + h] * ro;
      cenoff[(size_t)row * 8 + h] = tanhf(z) * 12.0f;
    }
  }
}

// ---------------------------------------------------------------------------
// rmsnorm over 512 + silu, in place (kernel projection)
// ---------------------------------------------------------------------------
__global__ __launch_bounds__(256) void rms_silu_kernel(
    float* __restrict__ kact, const float* __restrict__ gamma)
{
  const int row = blockIdx.x;
  const int t = threadIdx.x;
  float* kr = kact + (size_t)row * 512;
  float v0 = kr[t], v1 = kr[t + 256];
  float ss = v0 * v0 + v1 * v1;
#pragma unroll
  for (int off = 32; off >= 1; off >>= 1) ss += __shfl_xor(ss, off);
  __shared__ float red[4];
  const int wid = t >> 6, lane = t & 63;
  if (lane == 0) red[wid] = ss;
  __syncthreads();
  float tot = red[0] + red[1] + red[2] + red[3];
  float r = rsqrtf(tot * (1.f / 512.f) + 1e-6f);
  float a0 = gamma[t] * v0 * r;
  float a1 = gamma[t + 256] * v1 * r;
  kr[t]       = a0 / (1.f + expf(-a0));
  kr[t + 256] = a1 / (1.f + expf(-a1));
}

// ---------------------------------------------------------------------------
// deformable local conv: wave per (row, h), lane per d (D=64)
// ---------------------------------------------------------------------------
__global__ __launch_bounds__(256) void conv_kernel(
    const float* __restrict__ halfwin, const float* __restrict__ cenoff,
    const float* __restrict__ kact, const float* __restrict__ vbuf,
    float* __restrict__ outh)
{
  const int wid = threadIdx.x >> 6, lane = threadIdx.x & 63;
  const int gw  = blockIdx.x * 4 + wid;     // 0 .. BL*H-1
  const int row = gw >> 3, h = gw & 7;
  const int b   = row >> 12, l = row & 4095;
  const float hw = halfwin[gw];
  const float co = cenoff[gw];
  const float* kr = kact + (size_t)row * 512 + h * 64;
  const float* vb = vbuf + ((size_t)b * 4096) * 512 + h * 64 + lane;
  float acc = 0.f, wsum = 0.f;
#pragma unroll
  for (int si = 0; si < 13; si++) {
    const int soff = si - 6;
    float rel  = fabsf((float)soff) / hw;
    float ww   = __expf(-rel * rel);
    float npos = fminf(rel, 1.f) * 63.f;
    int   idx  = min((int)npos, 62);
    float wc   = npos - (float)idx;
    float kf = kr[idx], kc = kr[idx + 1];
    float kw = fmaxf(kf * (1.f - wc) + kc * wc, 0.f);
    float nb = (float)l + co + (float)soff;
    float w  = (nb >= 0.f && nb < 4096.f) ? (kw + 1.f) * ww : 0.f;
    wsum += w;
    float pc  = fminf(fmaxf(nb, 0.f), 4094.999f);
    int   pf  = (int)pc;                    // floor, pc >= 0
    float fr  = pc - (float)pf;
    int   pcl = min(pf + 1, 4095);
    float v0 = vb[(size_t)pf  * 512];
    float v1 = vb[(size_t)pcl * 512];
    acc += w * (v0 + fr * (v1 - v0));
  }
  outh[(size_t)row * 512 + h * 64 + lane] = acc / fmaxf(wsum, 1.f);
}

// ---------------------------------------------------------------------------
// column partial sums over L chunks (for the SE mean)
// ---------------------------------------------------------------------------
__global__ __launch_bounds__(256) void colpart_kernel(
    const float* __restrict__ outh, float* __restrict__ partial)
{
  const int blk = blockIdx.x;               // B*32
  const int b = blk >> 5, chunk = blk & 31;
  const int t = threadIdx.x;
  const float* base = outh + ((size_t)b * 4096 + (size_t)chunk * 128) * 512;
  float s0 = 0.f, s1 = 0.f;
  for (int i = 0; i < 128; i++) {
    s0 += base[(size_t)i * 512 + t];
    s1 += base[(size_t)i * 512 + 256 + t];
  }
  partial[(size_t)blk * 512 + t]       = s0;
  partial[(size_t)blk * 512 + 256 + t] = s1;
}

// ---------------------------------------------------------------------------
// SE MLP: mean -> silu(mean @ w1^T) -> sigmoid(.. @ w2^T) -> scale (B,512)
// single block, 1024 threads
// ---------------------------------------------------------------------------
__global__ __launch_bounds__(1024) void se_fwd_kernel(
    const float* __restrict__ partial,
    const float* __restrict__ w1, const float* __restrict__ w2,
    float* __restrict__ scalebuf)
{
  __shared__ float mean_s[2][512];
  __shared__ float hid_s[2][128];
  const int t = threadIdx.x;
  {
    const int b = t >> 9, c = t & 511;
    float m = 0.f;
    for (int ch = 0; ch < 32; ch++) m += partial[(size_t)(b * 32 + ch) * 512 + c];
    mean_s[b][c] = m * (1.f / 4096.f);
  }
  __syncthreads();
  const int wid = t >> 6, lane = t & 63;
#pragma unroll 1
  for (int i = 0; i < 16; i++) {
    const int o = wid * 16 + i;             // 0..255
    const int b2 = o >> 7, j = o & 127;
    float p = 0.f;
#pragma unroll
    for (int r = 0; r < 8; r++) p += mean_s[b2][lane + r * 64] * w1[(size_t)j * 512 + lane + r * 64];
#pragma unroll
    for (int off = 32; off >= 1; off >>= 1) p += __shfl_xor(p, off);
    if (lane == 0) hid_s[b2][j] = p / (1.f + expf(-p));
  }
  __syncthreads();
#pragma unroll 1
  for (int i = 0; i < 64; i++) {
    const int o = wid * 64 + i;             // 0..1023
    const int b3 = o >> 9, c = o & 511;
    float p = hid_s[b3][lane]      * w2[(size_t)c * 128 + lane]
            + hid_s[b3][64 + lane] * w2[(size_t)c * 128 + 64 + lane];
#pragma unroll
    for (int off = 32; off >= 1; off >>= 1) p += __shfl_xor(p, off);
    if (lane == 0) scalebuf[o] = 1.f / (1.f + expf(-p));
  }
}

// ---------------------------------------------------------------------------
extern "C" void kernel_launch(void* const* d_in, const int* in_sizes, int n_in,
                              void* d_out, int out_size, void* d_ws, size_t ws_size,
                              hipStream_t stream) {
  const float* x        = (const float*)d_in[0];
  const float* window_w = (const float*)d_in[1];
  const float* window_b = (const float*)d_in[2];
  const float* window_g = (const float*)d_in[3];
  const float* offset_w = (const float*)d_in[4];
  const float* offset_b = (const float*)d_in[5];
  const float* offset_g = (const float*)d_in[6];
  const float* kernel_w = (const float*)d_in[7];
  const float* kernel_b = (const float*)d_in[8];
  const float* kernel_g = (const float*)d_in[9];
  const float* v_w      = (const float*)d_in[10];
  const float* v_b      = (const float*)d_in[11];
  const float* se_w1    = (const float*)d_in[12];
  const float* se_w2    = (const float*)d_in[13];
  const float* out_w    = (const float*)d_in[14];
  float* out = (float*)d_out;
  float* ws  = (float*)d_ws;

  const size_t BLC = (size_t)8192 * 512;
  float* kact     = ws;                     // (BL,512) kernel proj -> activated
  float* vbuf     = kact + BLC;             // (BL,512) v
  float* outh     = vbuf + BLC;             // (BL,512) conv output (pre-SE)
  float* halfwin  = outh + BLC;             // (BL,8)
  float* cenoff   = halfwin + 65536;        // (BL,8)
  float* partial  = cenoff + 65536;         // (64,512)
  float* scalebuf = partial + 64 * 512;     // (2,512)

  // 1. kernel + v projections (fused dual GEMM over N=1024)
  gemm_nt<0><<<dim3(64, 8), 256, 0, stream>>>(x, kernel_w, v_w, kernel_b, v_b,
                                              kact, vbuf, nullptr);
  // 2. window/offset skinny projection + rmsnorm + sigmoid/tanh
  winoff_kernel<<<512, 256, 0, stream>>>(x, window_w, window_b, window_g,
                                         offset_w, offset_b, offset_g,
                                         halfwin, cenoff);
  // 3. rmsnorm + silu on kernel projection
  rms_silu_kernel<<<8192, 256, 0, stream>>>(kact, kernel_g);
  // 4. deformable conv
  conv_kernel<<<16384, 256, 0, stream>>>(halfwin, cenoff, kact, vbuf, outh);
  // 5-6. SE path
  colpart_kernel<<<64, 256, 0, stream>>>(outh, partial);
  se_fwd_kernel<<<1, 1024, 0, stream>>>(partial, se_w1, se_w2, scalebuf);
  // 7. final GEMM with per-(b,c) scale on A and silu epilogue
  gemm_nt<1><<<dim3(64, 4), 256, 0, stream>>>(outh, out_w, nullptr, nullptr, nullptr,
                                              out, nullptr, scalebuf);
}

// Round 2
// 203.961 us; speedup vs baseline: 1.5430x; 1.5430x over previous
//
#include <hip/hip_runtime.h>
#include <hip/hip_bf16.h>
#include <cstddef>
#include <cstdint>

// Problem constants (B=2, L=4096, C=512, H=8, K=64, D=64)
// max_window = 12, half_max = 6, S = 13, max_offset = 12.0, hid = 128

typedef short bf16x8 __attribute__((ext_vector_type(8)));
typedef float f32x4 __attribute__((ext_vector_type(4)));

#define AS1 __attribute__((address_space(1)))
#define AS3 __attribute__((address_space(3)))

__device__ __forceinline__ void gload_lds16(const ushort* g, ushort* l) {
  __builtin_amdgcn_global_load_lds((const AS1 uint32_t*)g, (AS3 uint32_t*)l, 16, 0, 0);
}

__device__ __forceinline__ ushort bf16_rne(float x) {
  uint32_t u = __float_as_uint(x);
  return (ushort)((u + 0x7fffu + ((u >> 16) & 1u)) >> 16);
}

// ---------------------------------------------------------------------------
// fp32 -> (hi, lo) bf16 split, vectorized float4
// ---------------------------------------------------------------------------
__global__ __launch_bounds__(256) void split_bf16(
    const float* __restrict__ src, ushort* __restrict__ hi,
    ushort* __restrict__ lo, int n4)
{
  for (int i = blockIdx.x * 256 + threadIdx.x; i < n4; i += gridDim.x * 256) {
    float4 v = ((const float4*)src)[i];
    float vv[4] = {v.x, v.y, v.z, v.w};
    ushort h[4], lw[4];
#pragma unroll
    for (int j = 0; j < 4; j++) {
      ushort hb = bf16_rne(vv[j]);
      float hf = __uint_as_float(((uint32_t)hb) << 16);
      h[j] = hb;
      lw[j] = bf16_rne(vv[j] - hf);
    }
    ushort4 hv = {h[0], h[1], h[2], h[3]};
    ushort4 lv = {lw[0], lw[1], lw[2], lw[3]};
    ((ushort4*)hi)[i] = hv;
    ((ushort4*)lo)[i] = lv;
  }
}

// ---------------------------------------------------------------------------
// outh * SE-scale -> (hi, lo) bf16 split   (scale per (b, c))
// ---------------------------------------------------------------------------
__global__ __launch_bounds__(256) void scale_split(
    const float* __restrict__ src, const float* __restrict__ scale,
    ushort* __restrict__ hi, ushort* __restrict__ lo)
{
  const int n4 = 8192 * 512 / 4;
  for (int i = blockIdx.x * 256 + threadIdx.x; i < n4; i += gridDim.x * 256) {
    int c4 = i & 127;
    int b  = (i >> 7) >> 12;
    float4 v = ((const float4*)src)[i];
    float4 s = ((const float4*)scale)[b * 128 + c4];
    float vv[4] = {v.x * s.x, v.y * s.y, v.z * s.z, v.w * s.w};
    ushort h[4], lw[4];
#pragma unroll
    for (int j = 0; j < 4; j++) {
      ushort hb = bf16_rne(vv[j]);
      float hf = __uint_as_float(((uint32_t)hb) << 16);
      h[j] = hb;
      lw[j] = bf16_rne(vv[j] - hf);
    }
    ushort4 hv = {h[0], h[1], h[2], h[3]};
    ushort4 lv = {lw[0], lw[1], lw[2], lw[3]};
    ((ushort4*)hi)[i] = hv;
    ((ushort4*)lo)[i] = lv;
  }
}

// ---------------------------------------------------------------------------
// MFMA GEMM (hi/lo split, fp32-equivalent): C[m,n] = sum_k A[m,k] * B[n,k]
// A: M x 512 (hi/lo bf16), B: N x 512 (hi/lo bf16). 128x128 tile, BK=32,
// 4 waves (2x2), 4x4 fragments of 16x16x32 per wave, 3 MFMAs per fragment.
// MODE 0: N=1024 -> cols <512 to Ck (+bk), >=512 to Cv (+bv)
// MODE 1: N=512  -> silu -> Ck
// ---------------------------------------------------------------------------
template<int MODE>
__global__ __launch_bounds__(256, 2) void gemm_mfma(
    const ushort* __restrict__ Ahi, const ushort* __restrict__ Alo,
    const ushort* __restrict__ Bhi, const ushort* __restrict__ Blo,
    const float* __restrict__ bk, const float* __restrict__ bv,
    float* __restrict__ Ck, float* __restrict__ Cv)
{
  __shared__ ushort smem[4 * 4096];   // Ahi | Alo | Bhi | Blo tiles (128x32 each)
  const int t   = threadIdx.x;
  const int wid = t >> 6, l = t & 63;
  const int m0  = blockIdx.x * 128;
  const int n0  = blockIdx.y * 128;

  // staging pointers: 8 x global_load_lds(16B) per K-step
  const ushort* gsrc[8];
  uint32_t loff[8];
  {
    const ushort* mp[4] = {Ahi, Alo, Bhi, Blo};
#pragma unroll
    for (int mat = 0; mat < 4; mat++) {
      int base = (mat < 2) ? m0 : n0;
#pragma unroll
      for (int i = 0; i < 2; i++) {
        int r = base + i * 64 + (t >> 2);
        gsrc[mat * 2 + i] = mp[mat] + (size_t)r * 512 + (t & 3) * 8;
        loff[mat * 2 + i] = mat * 4096 + i * 2048 + wid * 512;  // wave-uniform
      }
    }
  }

  f32x4 acc[4][4];
#pragma unroll
  for (int m = 0; m < 4; m++)
#pragma unroll
    for (int n = 0; n < 4; n++) acc[m][n] = (f32x4){0.f, 0.f, 0.f, 0.f};

  const int wr = wid >> 1, wc = wid & 1;
  const int fr = l & 15, fk = l >> 4;
  const int aoff = (wr * 64 + fr) * 32 + fk * 8;   // ushort index, + m*512
  const int boff = (wc * 64 + fr) * 32 + fk * 8;   // ushort index, + n*512

  for (int k0 = 0; k0 < 512; k0 += 32) {
#pragma unroll
    for (int j = 0; j < 8; j++) {
      gload_lds16(gsrc[j], &smem[loff[j]]);
      gsrc[j] += 32;
    }
    __syncthreads();   // drains vmcnt -> tiles resident

    bf16x8 ah[4], al[4], bh[4], bl[4];
#pragma unroll
    for (int m = 0; m < 4; m++) {
      ah[m] = *(const bf16x8*)&smem[0 * 4096 + aoff + m * 512];
      al[m] = *(const bf16x8*)&smem[1 * 4096 + aoff + m * 512];
    }
#pragma unroll
    for (int n = 0; n < 4; n++) {
      bh[n] = *(const bf16x8*)&smem[2 * 4096 + boff + n * 512];
      bl[n] = *(const bf16x8*)&smem[3 * 4096 + boff + n * 512];
    }
#pragma unroll
    for (int m = 0; m < 4; m++)
#pragma unroll
      for (int n = 0; n < 4; n++) {
        acc[m][n] = __builtin_amdgcn_mfma_f32_16x16x32_bf16(ah[m], bh[n], acc[m][n], 0, 0, 0);
        acc[m][n] = __builtin_amdgcn_mfma_f32_16x16x32_bf16(ah[m], bl[n], acc[m][n], 0, 0, 0);
        acc[m][n] = __builtin_amdgcn_mfma_f32_16x16x32_bf16(al[m], bh[n], acc[m][n], 0, 0, 0);
      }
    __syncthreads();   // all reads done before next stage overwrites
  }

  // epilogue: C/D layout col=lane&15, row=(lane>>4)*4+reg  [m89/m91]
  const int rbase = m0 + wr * 64 + (l >> 4) * 4;
  const int cbase = n0 + wc * 64 + (l & 15);
#pragma unroll
  for (int m = 0; m < 4; m++)
#pragma unroll
    for (int n = 0; n < 4; n++) {
      const int c = cbase + n * 16;
#pragma unroll
      for (int j = 0; j < 4; j++) {
        const int r = rbase + m * 16 + j;
        float v = acc[m][n][j];
        if (MODE == 0) {
          if (n0 < 512) Ck[(size_t)r * 512 + c] = v + bk[c];
          else          Cv[(size_t)r * 512 + (c - 512)] = v + bv[c - 512];
        } else {
          Ck[(size_t)r * 512 + c] = v / (1.f + expf(-v));
        }
      }
    }
}

// ---------------------------------------------------------------------------
// window / offset projection (N=16 skinny) + rmsnorm(H=8) + sigmoid/tanh
// ---------------------------------------------------------------------------
__global__ __launch_bounds__(256) void winoff_kernel(
    const float* __restrict__ x,
    const float* __restrict__ window_w, const float* __restrict__ window_b,
    const float* __restrict__ window_g,
    const float* __restrict__ offset_w, const float* __restrict__ offset_b,
    const float* __restrict__ offset_g,
    float* __restrict__ halfwin, float* __restrict__ cenoff)
{
  __shared__ float wsm[16][512];   // rows 0..7 window_w, 8..15 offset_w
  const int t = threadIdx.x;
  {
    float4* dst = (float4*)&wsm[0][0];
    for (int i = t; i < 2048; i += 256)
      dst[i] = (i < 1024) ? ((const float4*)window_w)[i] : ((const float4*)offset_w)[i - 1024];
  }
  __syncthreads();
  const int wid = t >> 6, lane = t & 63;
  for (int it = 0; it < 4; it++) {
    const int row = blockIdx.x * 16 + it * 4 + wid;
    const float* xr = x + (size_t)row * 512;
    float xv[8];
#pragma unroll
    for (int j = 0; j < 8; j++) xv[j] = xr[lane + j * 64];
    float s[16];
#pragma unroll
    for (int n = 0; n < 16; n++) {
      float p = 0.f;
#pragma unroll
      for (int j = 0; j < 8; j++) p += xv[j] * wsm[n][lane + j * 64];
#pragma unroll
      for (int off = 32; off >= 1; off >>= 1) p += __shfl_xor(p, off);
      s[n] = p;
    }
    float ssw = 0.f, sso = 0.f;
#pragma unroll
    for (int h = 0; h < 8; h++) {
      s[h]     += window_b[h]; ssw += s[h] * s[h];
      s[8 + h] += offset_b[h]; sso += s[8 + h] * s[8 + h];
    }
    float rw = rsqrtf(ssw * 0.125f + 1e-6f);
    float ro = rsqrtf(sso * 0.125f + 1e-6f);
    if (lane < 8) {
      float z  = window_g[lane] * s[lane] * rw;
      float wr = 1.f / (1.f + expf(-z));
      halfwin[(size_t)row * 8 + lane] = fmaxf((1.0f + wr * 11.0f) * 0.5f, 0.5f);
    } else if (lane < 16) {
      int h = lane - 8;
      float z = offset_g[h] * s[8 + h] * ro;
      cenoff[(size_t)row * 8 + h] = tanhf(z) * 12.0f;
    }
  }
}

// ---------------------------------------------------------------------------
// rmsnorm over 512 + silu, in place (kernel projection)
// ---------------------------------------------------------------------------
__global__ __launch_bounds__(256) void rms_silu_kernel(
    float* __restrict__ kact, const float* __restrict__ gamma)
{
  const int row = blockIdx.x;
  const int t = threadIdx.x;
  float* kr = kact + (size_t)row * 512;
  float v0 = kr[t], v1 = kr[t + 256];
  float ss = v0 * v0 + v1 * v1;
#pragma unroll
  for (int off = 32; off >= 1; off >>= 1) ss += __shfl_xor(ss, off);
  __shared__ float red[4];
  const int wid = t >> 6, lane = t & 63;
  if (lane == 0) red[wid] = ss;
  __syncthreads();
  float tot = red[0] + red[1] + red[2] + red[3];
  float r = rsqrtf(tot * (1.f / 512.f) + 1e-6f);
  float a0 = gamma[t] * v0 * r;
  float a1 = gamma[t + 256] * v1 * r;
  kr[t]       = a0 / (1.f + expf(-a0));
  kr[t + 256] = a1 / (1.f + expf(-a1));
}

// ---------------------------------------------------------------------------
// deformable local conv: wave per (row, h), lane per d (D=64)
// ---------------------------------------------------------------------------
__global__ __launch_bounds__(256) void conv_kernel(
    const float* __restrict__ halfwin, const float* __restrict__ cenoff,
    const float* __restrict__ kact, const float* __restrict__ vbuf,
    float* __restrict__ outh)
{
  const int wid = threadIdx.x >> 6, lane = threadIdx.x & 63;
  const int gw  = blockIdx.x * 4 + wid;     // 0 .. BL*H-1
  const int row = gw >> 3, h = gw & 7;
  const int b   = row >> 12, l = row & 4095;
  const float hw = halfwin[gw];
  const float co = cenoff[gw];
  const float* kr = kact + (size_t)row * 512 + h * 64;
  const float* vb = vbuf + ((size_t)b * 4096) * 512 + h * 64 + lane;
  float acc = 0.f, wsum = 0.f;
#pragma unroll
  for (int si = 0; si < 13; si++) {
    const int soff = si - 6;
    float rel  = fabsf((float)soff) / hw;
    float ww   = __expf(-rel * rel);
    float npos = fminf(rel, 1.f) * 63.f;
    int   idx  = min((int)npos, 62);
    float wc   = npos - (float)idx;
    float kf = kr[idx], kc = kr[idx + 1];
    float kw = fmaxf(kf * (1.f - wc) + kc * wc, 0.f);
    float nb = (float)l + co + (float)soff;
    float w  = (nb >= 0.f && nb < 4096.f) ? (kw + 1.f) * ww : 0.f;
    wsum += w;
    float pc  = fminf(fmaxf(nb, 0.f), 4094.999f);
    int   pf  = (int)pc;                    // floor, pc >= 0
    float fr  = pc - (float)pf;
    int   pcl = min(pf + 1, 4095);
    float v0 = vb[(size_t)pf  * 512];
    float v1 = vb[(size_t)pcl * 512];
    acc += w * (v0 + fr * (v1 - v0));
  }
  outh[(size_t)row * 512 + h * 64 + lane] = acc / fmaxf(wsum, 1.f);
}

// ---------------------------------------------------------------------------
// column partial sums over L chunks (for the SE mean)
// ---------------------------------------------------------------------------
__global__ __launch_bounds__(256) void colpart_kernel(
    const float* __restrict__ outh, float* __restrict__ partial)
{
  const int blk = blockIdx.x;               // B*32
  const int b = blk >> 5, chunk = blk & 31;
  const int t = threadIdx.x;
  const float* base = outh + ((size_t)b * 4096 + (size_t)chunk * 128) * 512;
  float s0 = 0.f, s1 = 0.f;
  for (int i = 0; i < 128; i++) {
    s0 += base[(size_t)i * 512 + t];
    s1 += base[(size_t)i * 512 + 256 + t];
  }
  partial[(size_t)blk * 512 + t]       = s0;
  partial[(size_t)blk * 512 + 256 + t] = s1;
}

// ---------------------------------------------------------------------------
// SE MLP: mean -> silu(mean @ w1^T) -> sigmoid(.. @ w2^T) -> scale (B,512)
// ---------------------------------------------------------------------------
__global__ __launch_bounds__(1024) void se_fwd_kernel(
    const float* __restrict__ partial,
    const float* __restrict__ w1, const float* __restrict__ w2,
    float* __restrict__ scalebuf)
{
  __shared__ float mean_s[2][512];
  __shared__ float hid_s[2][128];
  const int t = threadIdx.x;
  {
    const int b = t >> 9, c = t & 511;
    float m = 0.f;
    for (int ch = 0; ch < 32; ch++) m += partial[(size_t)(b * 32 + ch) * 512 + c];
    mean_s[b][c] = m * (1.f / 4096.f);
  }
  __syncthreads();
  const int wid = t >> 6, lane = t & 63;
#pragma unroll 1
  for (int i = 0; i < 16; i++) {
    const int o = wid * 16 + i;             // 0..255
    const int b2 = o >> 7, j = o & 127;
    float p = 0.f;
#pragma unroll
    for (int r = 0; r < 8; r++) p += mean_s[b2][lane + r * 64] * w1[(size_t)j * 512 + lane + r * 64];
#pragma unroll
    for (int off = 32; off >= 1; off >>= 1) p += __shfl_xor(p, off);
    if (lane == 0) hid_s[b2][j] = p / (1.f + expf(-p));
  }
  __syncthreads();
#pragma unroll 1
  for (int i = 0; i < 64; i++) {
    const int o = wid * 64 + i;             // 0..1023
    const int b3 = o >> 9, c = o & 511;
    float p = hid_s[b3][lane]      * w2[(size_t)c * 128 + lane]
            + hid_s[b3][64 + lane] * w2[(size_t)c * 128 + 64 + lane];
#pragma unroll
    for (int off = 32; off >= 1; off >>= 1) p += __shfl_xor(p, off);
    if (lane == 0) scalebuf[o] = 1.f / (1.f + expf(-p));
  }
}

// ---------------------------------------------------------------------------
extern "C" void kernel_launch(void* const* d_in, const int* in_sizes, int n_in,
                              void* d_out, int out_size, void* d_ws, size_t ws_size,
                              hipStream_t stream) {
  const float* x        = (const float*)d_in[0];
  const float* window_w = (const float*)d_in[1];
  const float* window_b = (const float*)d_in[2];
  const float* window_g = (const float*)d_in[3];
  const float* offset_w = (const float*)d_in[4];
  const float* offset_b = (const float*)d_in[5];
  const float* offset_g = (const float*)d_in[6];
  const float* kernel_w = (const float*)d_in[7];
  const float* kernel_b = (const float*)d_in[8];
  const float* kernel_g = (const float*)d_in[9];
  const float* v_w      = (const float*)d_in[10];
  const float* v_b      = (const float*)d_in[11];
  const float* se_w1    = (const float*)d_in[12];
  const float* se_w2    = (const float*)d_in[13];
  const float* out_w    = (const float*)d_in[14];
  float* out = (float*)d_out;
  char* ws   = (char*)d_ws;

  const size_t BLC = (size_t)8192 * 512;
  float* kact     = (float*)ws;                       ws += BLC * 4;   // (BL,512)
  float* vbuf     = (float*)ws;                       ws += BLC * 4;   // (BL,512)
  float* outh     = (float*)ws;                       ws += BLC * 4;   // (BL,512)
  float* halfwin  = (float*)ws;                       ws += 65536 * 4;
  float* cenoff   = (float*)ws;                       ws += 65536 * 4;
  float* partial  = (float*)ws;                       ws += 64 * 512 * 4;
  float* scalebuf = (float*)ws;                       ws += 1024 * 4;
  ushort* xhi     = (ushort*)ws;                      ws += BLC * 2;   // aliased: oh_hi
  ushort* xlo     = (ushort*)ws;                      ws += BLC * 2;   // aliased: oh_lo
  ushort* wkvhi   = (ushort*)ws;                      ws += 1024 * 512 * 2;
  ushort* wkvlo   = (ushort*)ws;                      ws += 1024 * 512 * 2;
  ushort* owhi    = (ushort*)ws;                      ws += 512 * 512 * 2;
  ushort* owlo    = (ushort*)ws;                      ws += 512 * 512 * 2;

  // 0. bf16 hi/lo conversions
  split_bf16<<<2048, 256, 0, stream>>>(x, xhi, xlo, 1048576);
  split_bf16<<<256, 256, 0, stream>>>(kernel_w, wkvhi, wkvlo, 65536);
  split_bf16<<<256, 256, 0, stream>>>(v_w, wkvhi + 262144, wkvlo + 262144, 65536);
  split_bf16<<<256, 256, 0, stream>>>(out_w, owhi, owlo, 65536);

  // 1. kernel + v projections (fused dual MFMA GEMM over N=1024)
  gemm_mfma<0><<<dim3(64, 8), 256, 0, stream>>>(xhi, xlo, wkvhi, wkvlo,
                                                kernel_b, v_b, kact, vbuf);
  // 2. window/offset skinny projection + rmsnorm + sigmoid/tanh
  winoff_kernel<<<512, 256, 0, stream>>>(x, window_w, window_b, window_g,
                                         offset_w, offset_b, offset_g,
                                         halfwin, cenoff);
  // 3. rmsnorm + silu on kernel projection
  rms_silu_kernel<<<8192, 256, 0, stream>>>(kact, kernel_g);
  // 4. deformable conv
  conv_kernel<<<16384, 256, 0, stream>>>(halfwin, cenoff, kact, vbuf, outh);
  // 5-6. SE path
  colpart_kernel<<<64, 256, 0, stream>>>(outh, partial);
  se_fwd_kernel<<<1, 1024, 0, stream>>>(partial, se_w1, se_w2, scalebuf);
  // 7. fold SE scale into outh, split to bf16 (reuse xhi/xlo space)
  scale_split<<<2048, 256, 0, stream>>>(outh, scalebuf, xhi, xlo);
  // 8. final MFMA GEMM + silu
  gemm_mfma<1><<<dim3(64, 4), 256, 0, stream>>>(xhi, xlo, owhi, owlo,
                                                nullptr, nullptr, out, nullptr);
}

// Round 3
// 165.167 us; speedup vs baseline: 1.9054x; 1.2349x over previous
//
#include <hip/hip_runtime.h>
#include <hip/hip_bf16.h>
#include <cstddef>
#include <cstdint>

// Problem constants (B=2, L=4096, C=512, H=8, K=64, D=64)
// max_window = 12, half_max = 6, S = 13, max_offset = 12.0, hid = 128

typedef short bf16x8 __attribute__((ext_vector_type(8)));
typedef float f32x4 __attribute__((ext_vector_type(4)));

#define AS1 __attribute__((address_space(1)))
#define AS3 __attribute__((address_space(3)))

__device__ __forceinline__ void gload_lds16(const ushort* g, ushort* l) {
  __builtin_amdgcn_global_load_lds((const AS1 uint32_t*)g, (AS3 uint32_t*)l, 16, 0, 0);
}

__device__ __forceinline__ ushort bf16_rne(float x) {
  uint32_t u = __float_as_uint(x);
  return (ushort)((u + 0x7fffu + ((u >> 16) & 1u)) >> 16);
}
__device__ __forceinline__ float bf2f(ushort u) {
  return __uint_as_float(((uint32_t)u) << 16);
}
__device__ __forceinline__ float readlane_f(float v, int l) {
  return __int_as_float(__builtin_amdgcn_readlane(__float_as_int(v), l));
}

// ---------------------------------------------------------------------------
// fp32 -> (hi, lo) bf16 split, vectorized float4
// ---------------------------------------------------------------------------
__global__ __launch_bounds__(256) void split_bf16(
    const float* __restrict__ src, ushort* __restrict__ hi,
    ushort* __restrict__ lo, int n4)
{
  for (int i = blockIdx.x * 256 + threadIdx.x; i < n4; i += gridDim.x * 256) {
    float4 v = ((const float4*)src)[i];
    float vv[4] = {v.x, v.y, v.z, v.w};
    ushort h[4], lw[4];
#pragma unroll
    for (int j = 0; j < 4; j++) {
      ushort hb = bf16_rne(vv[j]);
      h[j] = hb;
      lw[j] = bf16_rne(vv[j] - bf2f(hb));
    }
    ushort4 hv = {h[0], h[1], h[2], h[3]};
    ushort4 lv = {lw[0], lw[1], lw[2], lw[3]};
    ((ushort4*)hi)[i] = hv;
    ((ushort4*)lo)[i] = lv;
  }
}

// ---------------------------------------------------------------------------
// out_w * SE-scale -> per-batch (hi, lo) bf16   ( w'[b][n][c] = w[n][c]*s[b][c] )
// ---------------------------------------------------------------------------
__global__ __launch_bounds__(256) void scale_w_kernel(
    const float* __restrict__ out_w, const float* __restrict__ scalebuf,
    ushort* __restrict__ hi, ushort* __restrict__ lo)
{
  const int i = blockIdx.x * 256 + threadIdx.x;   // 131072 = 2 * 65536 float4
  const int b = i >> 16, iw = i & 65535, c4 = i & 127;
  float4 v = ((const float4*)out_w)[iw];
  float4 s = ((const float4*)scalebuf)[b * 128 + c4];
  float vv[4] = {v.x * s.x, v.y * s.y, v.z * s.z, v.w * s.w};
  ushort h[4], lw[4];
#pragma unroll
  for (int j = 0; j < 4; j++) {
    ushort hb = bf16_rne(vv[j]);
    h[j] = hb;
    lw[j] = bf16_rne(vv[j] - bf2f(hb));
  }
  ushort4 hv = {h[0], h[1], h[2], h[3]};
  ushort4 lv = {lw[0], lw[1], lw[2], lw[3]};
  ((ushort4*)hi)[i] = hv;
  ((ushort4*)lo)[i] = lv;
}

// ---------------------------------------------------------------------------
// MFMA GEMM (hi/lo split, fp32-equivalent): C[m,n] = sum_k A[m,k] * B[n,k]
// 128x128 tile, BK=32, 4 waves (2x2), 4x4 fragments of 16x16x32, 3 MFMA each.
// MODE 0: N=1024 -> cols <512 to Ck (+bk), >=512 to Cv (+bv)
// MODE 1: N=512, B has per-batch offset (m0>>12)*2^18 -> silu -> Ck
// ---------------------------------------------------------------------------
template<int MODE>
__global__ __launch_bounds__(256, 2) void gemm_mfma(
    const ushort* __restrict__ Ahi, const ushort* __restrict__ Alo,
    const ushort* __restrict__ Bhi, const ushort* __restrict__ Blo,
    const float* __restrict__ bk, const float* __restrict__ bv,
    float* __restrict__ Ck, float* __restrict__ Cv)
{
  __shared__ ushort smem[4 * 4096];   // Ahi | Alo | Bhi | Blo tiles (128x32 each)
  const int t   = threadIdx.x;
  const int wid = t >> 6, l = t & 63;
  const int m0  = blockIdx.x * 128;
  const int n0  = blockIdx.y * 128;

  const ushort* Bh = Bhi;
  const ushort* Bl = Blo;
  if (MODE == 1) {
    size_t off = (size_t)(m0 >> 12) << 18;   // batch * 512*512
    Bh += off; Bl += off;
  }

  // staging pointers: 8 x global_load_lds(16B) per K-step
  const ushort* gsrc[8];
  uint32_t loff[8];
  {
    const ushort* mp[4] = {Ahi, Alo, Bh, Bl};
#pragma unroll
    for (int mat = 0; mat < 4; mat++) {
      int base = (mat < 2) ? m0 : n0;
#pragma unroll
      for (int i = 0; i < 2; i++) {
        int r = base + i * 64 + (t >> 2);
        gsrc[mat * 2 + i] = mp[mat] + (size_t)r * 512 + (t & 3) * 8;
        loff[mat * 2 + i] = mat * 4096 + i * 2048 + wid * 512;  // wave-uniform
      }
    }
  }

  f32x4 acc[4][4];
#pragma unroll
  for (int m = 0; m < 4; m++)
#pragma unroll
    for (int n = 0; n < 4; n++) acc[m][n] = (f32x4){0.f, 0.f, 0.f, 0.f};

  const int wr = wid >> 1, wc = wid & 1;
  const int fr = l & 15, fk = l >> 4;
  const int aoff = (wr * 64 + fr) * 32 + fk * 8;   // ushort index, + m*512
  const int boff = (wc * 64 + fr) * 32 + fk * 8;   // ushort index, + n*512

  for (int k0 = 0; k0 < 512; k0 += 32) {
#pragma unroll
    for (int j = 0; j < 8; j++) {
      gload_lds16(gsrc[j], &smem[loff[j]]);
      gsrc[j] += 32;
    }
    __syncthreads();   // drains vmcnt -> tiles resident

    bf16x8 ah[4], al[4], bh[4], bl[4];
#pragma unroll
    for (int m = 0; m < 4; m++) {
      ah[m] = *(const bf16x8*)&smem[0 * 4096 + aoff + m * 512];
      al[m] = *(const bf16x8*)&smem[1 * 4096 + aoff + m * 512];
    }
#pragma unroll
    for (int n = 0; n < 4; n++) {
      bh[n] = *(const bf16x8*)&smem[2 * 4096 + boff + n * 512];
      bl[n] = *(const bf16x8*)&smem[3 * 4096 + boff + n * 512];
    }
#pragma unroll
    for (int m = 0; m < 4; m++)
#pragma unroll
      for (int n = 0; n < 4; n++) {
        acc[m][n] = __builtin_amdgcn_mfma_f32_16x16x32_bf16(ah[m], bh[n], acc[m][n], 0, 0, 0);
        acc[m][n] = __builtin_amdgcn_mfma_f32_16x16x32_bf16(ah[m], bl[n], acc[m][n], 0, 0, 0);
        acc[m][n] = __builtin_amdgcn_mfma_f32_16x16x32_bf16(al[m], bh[n], acc[m][n], 0, 0, 0);
      }
    __syncthreads();   // all reads done before next stage overwrites
  }

  // epilogue: C/D layout col=lane&15, row=(lane>>4)*4+reg  [m89/m91]
  const int rbase = m0 + wr * 64 + (l >> 4) * 4;
  const int cbase = n0 + wc * 64 + (l & 15);
#pragma unroll
  for (int m = 0; m < 4; m++)
#pragma unroll
    for (int n = 0; n < 4; n++) {
      const int c = cbase + n * 16;
#pragma unroll
      for (int j = 0; j < 4; j++) {
        const int r = rbase + m * 16 + j;
        float v = acc[m][n][j];
        if (MODE == 0) {
          if (n0 < 512) Ck[(size_t)r * 512 + c] = v + bk[c];
          else          Cv[(size_t)r * 512 + (c - 512)] = v + bv[c - 512];
        } else {
          Ck[(size_t)r * 512 + c] = v / (1.f + expf(-v));
        }
      }
    }
}

// ---------------------------------------------------------------------------
// window / offset projection (N=16 skinny) + rmsnorm(H=8) + sigmoid/tanh
// ---------------------------------------------------------------------------
__global__ __launch_bounds__(256) void winoff_kernel(
    const float* __restrict__ x,
    const float* __restrict__ window_w, const float* __restrict__ window_b,
    const float* __restrict__ window_g,
    const float* __restrict__ offset_w, const float* __restrict__ offset_b,
    const float* __restrict__ offset_g,
    float* __restrict__ halfwin, float* __restrict__ cenoff)
{
  __shared__ float wsm[16][512];   // rows 0..7 window_w, 8..15 offset_w
  const int t = threadIdx.x;
  {
    float4* dst = (float4*)&wsm[0][0];
    for (int i = t; i < 2048; i += 256)
      dst[i] = (i < 1024) ? ((const float4*)window_w)[i] : ((const float4*)offset_w)[i - 1024];
  }
  __syncthreads();
  const int wid = t >> 6, lane = t & 63;
  for (int it = 0; it < 4; it++) {
    const int row = blockIdx.x * 16 + it * 4 + wid;
    const float* xr = x + (size_t)row * 512;
    float xv[8];
#pragma unroll
    for (int j = 0; j < 8; j++) xv[j] = xr[lane + j * 64];
    float s[16];
#pragma unroll
    for (int n = 0; n < 16; n++) {
      float p = 0.f;
#pragma unroll
      for (int j = 0; j < 8; j++) p += xv[j] * wsm[n][lane + j * 64];
#pragma unroll
      for (int off = 32; off >= 1; off >>= 1) p += __shfl_xor(p, off);
      s[n] = p;
    }
    float ssw = 0.f, sso = 0.f;
#pragma unroll
    for (int h = 0; h < 8; h++) {
      s[h]     += window_b[h]; ssw += s[h] * s[h];
      s[8 + h] += offset_b[h]; sso += s[8 + h] * s[8 + h];
    }
    float rw = rsqrtf(ssw * 0.125f + 1e-6f);
    float ro = rsqrtf(sso * 0.125f + 1e-6f);
    if (lane < 8) {
      float z  = window_g[lane] * s[lane] * rw;
      float wr2 = 1.f / (1.f + expf(-z));
      halfwin[(size_t)row * 8 + lane] = fmaxf((1.0f + wr2 * 11.0f) * 0.5f, 0.5f);
    } else if (lane < 16) {
      int h = lane - 8;
      float z = offset_g[h] * s[8 + h] * ro;
      cenoff[(size_t)row * 8 + h] = tanhf(z) * 12.0f;
    }
  }
}

// ---------------------------------------------------------------------------
// rmsnorm over 512 + silu, in place (kernel projection)
// ---------------------------------------------------------------------------
__global__ __launch_bounds__(256) void rms_silu_kernel(
    float* __restrict__ kact, const float* __restrict__ gamma)
{
  const int row = blockIdx.x;
  const int t = threadIdx.x;
  float* kr = kact + (size_t)row * 512;
  float v0 = kr[t], v1 = kr[t + 256];
  float ss = v0 * v0 + v1 * v1;
#pragma unroll
  for (int off = 32; off >= 1; off >>= 1) ss += __shfl_xor(ss, off);
  __shared__ float red[4];
  const int wid = t >> 6, lane = t & 63;
  if (lane == 0) red[wid] = ss;
  __syncthreads();
  float tot = red[0] + red[1] + red[2] + red[3];
  float r = rsqrtf(tot * (1.f / 512.f) + 1e-6f);
  float a0 = gamma[t] * v0 * r;
  float a1 = gamma[t + 256] * v1 * r;
  kr[t]       = a0 / (1.f + expf(-a0));
  kr[t + 256] = a1 / (1.f + expf(-a1));
}

// ---------------------------------------------------------------------------
// deformable local conv: wave per (row, h), lane per d (D=64)
// lanes 0..12 compute the 13 offset weights in parallel; main loop broadcasts
// them via readlane (SGPR) so per-offset work is ~3 readlane + 2 loads + FMAs.
// Output written directly as hi/lo bf16 (GEMM1 A operand).
// ---------------------------------------------------------------------------
__global__ __launch_bounds__(256) void conv_kernel(
    const float* __restrict__ halfwin, const float* __restrict__ cenoff,
    const float* __restrict__ kact, const float* __restrict__ vbuf,
    ushort* __restrict__ oh_hi, ushort* __restrict__ oh_lo)
{
  const int wid = threadIdx.x >> 6, lane = threadIdx.x & 63;
  const int gw  = blockIdx.x * 4 + wid;     // 0 .. BL*H-1
  const int row = gw >> 3, h = gw & 7;
  const int b   = row >> 12, l = row & 4095;
  const float hw = halfwin[gw];
  const float co = cenoff[gw];
  const float* kr = kact + (size_t)row * 512 + h * 64;
  const float* vbase = vbuf + ((size_t)b * 4096) * 512 + h * 64;  // + pf*512 + lane

  // weight phase: lane si in [0,13)
  float w = 0.f, frv = 0.f;
  int pfv = 0;
  if (lane < 13) {
    const int soff = lane - 6;
    float rel  = fabsf((float)soff) / hw;
    float ww   = __expf(-rel * rel);
    float npos = fminf(rel, 1.f) * 63.f;
    int   idx  = min((int)npos, 62);
    float wc   = npos - (float)idx;
    float kf = kr[idx], kc = kr[idx + 1];
    float kw = fmaxf(kf * (1.f - wc) + kc * wc, 0.f);
    float nb = (float)l + co + (float)soff;
    w = (nb >= 0.f && nb < 4096.f) ? (kw + 1.f) * ww : 0.f;
    float pc = fminf(fmaxf(nb, 0.f), 4094.999f);
    pfv = (int)pc;
    frv = pc - (float)pfv;
  }
  float wsum = w;
#pragma unroll
  for (int off = 32; off >= 1; off >>= 1) wsum += __shfl_xor(wsum, off);

  float acc = 0.f;
#pragma unroll
  for (int si = 0; si < 13; si++) {
    const float w_s  = readlane_f(w, si);
    const float fr_s = readlane_f(frv, si);
    const int   pf_s = __builtin_amdgcn_readlane(pfv, si);
    const float* vrow = vbase + (size_t)pf_s * 512;   // uniform -> SGPR base
    float v0 = vrow[lane];
    float v1 = vrow[lane + 512];                      // pf_s <= 4094 always
    float t0 = v0 + fr_s * (v1 - v0);
    acc = fmaf(w_s, t0, acc);
  }

  float val = acc / fmaxf(wsum, 1.f);
  ushort hb = bf16_rne(val);
  ushort lb = bf16_rne(val - bf2f(hb));
  oh_hi[(size_t)row * 512 + h * 64 + lane] = hb;
  oh_lo[(size_t)row * 512 + h * 64 + lane] = lb;
}

// ---------------------------------------------------------------------------
// column partial sums over L chunks (for the SE mean), reads hi/lo bf16
// ---------------------------------------------------------------------------
__global__ __launch_bounds__(256) void colpart_kernel(
    const ushort* __restrict__ oh_hi, const ushort* __restrict__ oh_lo,
    float* __restrict__ partial)
{
  const int blk = blockIdx.x;               // B*32
  const int b = blk >> 5, chunk = blk & 31;
  const int t = threadIdx.x;
  const size_t base = ((size_t)b * 4096 + (size_t)chunk * 128) * 512;
  float s0 = 0.f, s1 = 0.f;
  for (int i = 0; i < 128; i++) {
    const size_t o = base + (size_t)i * 512;
    s0 += bf2f(oh_hi[o + t])       + bf2f(oh_lo[o + t]);
    s1 += bf2f(oh_hi[o + 256 + t]) + bf2f(oh_lo[o + 256 + t]);
  }
  partial[(size_t)blk * 512 + t]       = s0;
  partial[(size_t)blk * 512 + 256 + t] = s1;
}

// ---------------------------------------------------------------------------
// SE MLP: mean -> silu(mean @ w1^T) -> sigmoid(.. @ w2^T) -> scale (B,512)
// single block, 1024 threads; ILP-structured (unrolled, multi-accumulator)
// ---------------------------------------------------------------------------
__global__ __launch_bounds__(1024) void se_fwd_kernel(
    const float* __restrict__ partial,
    const float* __restrict__ w1, const float* __restrict__ w2,
    float* __restrict__ scalebuf)
{
  __shared__ float mean_s[2][512];
  __shared__ float hid_s[2][128];
  const int t = threadIdx.x;
  {
    const int b = t >> 9, c = t & 511;
    float m = 0.f;
#pragma unroll
    for (int ch = 0; ch < 32; ch++) m += partial[(size_t)(b * 32 + ch) * 512 + c];
    mean_s[b][c] = m * (1.f / 4096.f);
  }
  __syncthreads();
  if (t < 256) {                             // one thread per hidden unit
    const int b2 = t >> 7, j = t & 127;
    const float4* wr = (const float4*)(w1 + (size_t)j * 512);
    const float4* mr = (const float4*)&mean_s[b2][0];
    float ac[4] = {0.f, 0.f, 0.f, 0.f};
    for (int ro = 0; ro < 128; ro += 16) {
#pragma unroll
      for (int q = 0; q < 16; q++) {
        float4 wv = wr[ro + q];
        float4 mv = mr[ro + q];
        ac[q & 3] += wv.x * mv.x + wv.y * mv.y + wv.z * mv.z + wv.w * mv.w;
      }
    }
    float p = ac[0] + ac[1] + ac[2] + ac[3];
    hid_s[b2][j] = p / (1.f + expf(-p));
  }
  __syncthreads();
  {                                          // one thread per output channel
    const int b3 = t >> 9, c = t & 511;
    const float4* wr = (const float4*)(w2 + (size_t)c * 128);
    const float4* hr = (const float4*)&hid_s[b3][0];
    float ac[4] = {0.f, 0.f, 0.f, 0.f};
#pragma unroll
    for (int q = 0; q < 32; q++) {
      float4 wv = wr[q];
      float4 hv = hr[q];
      ac[q & 3] += wv.x * hv.x + wv.y * hv.y + wv.z * hv.z + wv.w * hv.w;
    }
    float p = ac[0] + ac[1] + ac[2] + ac[3];
    scalebuf[t] = 1.f / (1.f + expf(-p));
  }
}

// ---------------------------------------------------------------------------
extern "C" void kernel_launch(void* const* d_in, const int* in_sizes, int n_in,
                              void* d_out, int out_size, void* d_ws, size_t ws_size,
                              hipStream_t stream) {
  const float* x        = (const float*)d_in[0];
  const float* window_w = (const float*)d_in[1];
  const float* window_b = (const float*)d_in[2];
  const float* window_g = (const float*)d_in[3];
  const float* offset_w = (const float*)d_in[4];
  const float* offset_b = (const float*)d_in[5];
  const float* offset_g = (const float*)d_in[6];
  const float* kernel_w = (const float*)d_in[7];
  const float* kernel_b = (const float*)d_in[8];
  const float* kernel_g = (const float*)d_in[9];
  const float* v_w      = (const float*)d_in[10];
  const float* v_b      = (const float*)d_in[11];
  const float* se_w1    = (const float*)d_in[12];
  const float* se_w2    = (const float*)d_in[13];
  const float* out_w    = (const float*)d_in[14];
  float* out = (float*)d_out;
  char* ws   = (char*)d_ws;

  const size_t BLC = (size_t)8192 * 512;
  float* kact     = (float*)ws;                       ws += BLC * 4;   // (BL,512)
  float* vbuf     = (float*)ws;                       ws += BLC * 4;   // (BL,512)
  float* halfwin  = (float*)ws;                       ws += 65536 * 4;
  float* cenoff   = (float*)ws;                       ws += 65536 * 4;
  float* partial  = (float*)ws;                       ws += 64 * 512 * 4;
  float* scalebuf = (float*)ws;                       ws += 1024 * 4;
  ushort* xhi     = (ushort*)ws;                      ws += BLC * 2;
  ushort* xlo     = (ushort*)ws;                      ws += BLC * 2;
  ushort* wkvhi   = (ushort*)ws;                      ws += 1024 * 512 * 2;
  ushort* wkvlo   = (ushort*)ws;                      ws += 1024 * 512 * 2;
  ushort* oh_hi   = (ushort*)ws;                      ws += BLC * 2;
  ushort* oh_lo   = (ushort*)ws;                      ws += BLC * 2;
  ushort* owshi   = (ushort*)ws;                      ws += 2 * 512 * 512 * 2;
  ushort* owslo   = (ushort*)ws;                      ws += 2 * 512 * 512 * 2;

  // 0. bf16 hi/lo conversions
  split_bf16<<<2048, 256, 0, stream>>>(x, xhi, xlo, 1048576);
  split_bf16<<<256, 256, 0, stream>>>(kernel_w, wkvhi, wkvlo, 65536);
  split_bf16<<<256, 256, 0, stream>>>(v_w, wkvhi + 262144, wkvlo + 262144, 65536);

  // 1. kernel + v projections (fused dual MFMA GEMM over N=1024)
  gemm_mfma<0><<<dim3(64, 8), 256, 0, stream>>>(xhi, xlo, wkvhi, wkvlo,
                                                kernel_b, v_b, kact, vbuf);
  // 2. window/offset skinny projection + rmsnorm + sigmoid/tanh
  winoff_kernel<<<512, 256, 0, stream>>>(x, window_w, window_b, window_g,
                                         offset_w, offset_b, offset_g,
                                         halfwin, cenoff);
  // 3. rmsnorm + silu on kernel projection
  rms_silu_kernel<<<8192, 256, 0, stream>>>(kact, kernel_g);
  // 4. deformable conv -> hi/lo bf16 output
  conv_kernel<<<16384, 256, 0, stream>>>(halfwin, cenoff, kact, vbuf, oh_hi, oh_lo);
  // 5-6. SE path
  colpart_kernel<<<64, 256, 0, stream>>>(oh_hi, oh_lo, partial);
  se_fwd_kernel<<<1, 1024, 0, stream>>>(partial, se_w1, se_w2, scalebuf);
  // 7. fold SE scale into out_w (per batch), split to bf16
  scale_w_kernel<<<512, 256, 0, stream>>>(out_w, scalebuf, owshi, owslo);
  // 8. final MFMA GEMM + silu (A = conv output hi/lo, B = scaled out_w)
  gemm_mfma<1><<<dim3(64, 4), 256, 0, stream>>>(oh_hi, oh_lo, owshi, owslo,
                                                nullptr, nullptr, out, nullptr);
}

// Round 4
// 133.019 us; speedup vs baseline: 2.3659x; 1.2417x over previous
//
#include <hip/hip_runtime.h>
#include <hip/hip_bf16.h>
#include <cstddef>
#include <cstdint>

// Problem constants (B=2, L=4096, C=512, H=8, K=64, D=64)
// max_window = 12, half_max = 6, S = 13, max_offset = 12.0, hid = 128

typedef short bf16x8 __attribute__((ext_vector_type(8)));
typedef float f32x4 __attribute__((ext_vector_type(4)));

#define AS1 __attribute__((address_space(1)))
#define AS3 __attribute__((address_space(3)))

__device__ __forceinline__ void gload_lds16(const ushort* g, ushort* l) {
  __builtin_amdgcn_global_load_lds((const AS1 uint32_t*)g, (AS3 uint32_t*)l, 16, 0, 0);
}

__device__ __forceinline__ ushort bf16_rne(float x) {
  uint32_t u = __float_as_uint(x);
  return (ushort)((u + 0x7fffu + ((u >> 16) & 1u)) >> 16);
}
__device__ __forceinline__ float bf2f(ushort u) {
  return __uint_as_float(((uint32_t)u) << 16);
}
__device__ __forceinline__ float readlane_f(float v, int l) {
  return __int_as_float(__builtin_amdgcn_readlane(__float_as_int(v), l));
}

// ---------------------------------------------------------------------------
// fp32 -> (hi, lo) bf16 split, vectorized float4  (weights only now)
// ---------------------------------------------------------------------------
__global__ __launch_bounds__(256) void split_bf16(
    const float* __restrict__ src, ushort* __restrict__ hi,
    ushort* __restrict__ lo, int n4)
{
  for (int i = blockIdx.x * 256 + threadIdx.x; i < n4; i += gridDim.x * 256) {
    float4 v = ((const float4*)src)[i];
    float vv[4] = {v.x, v.y, v.z, v.w};
    ushort h[4], lw[4];
#pragma unroll
    for (int j = 0; j < 4; j++) {
      ushort hb = bf16_rne(vv[j]);
      h[j] = hb;
      lw[j] = bf16_rne(vv[j] - bf2f(hb));
    }
    ushort4 hv = {h[0], h[1], h[2], h[3]};
    ushort4 lv = {lw[0], lw[1], lw[2], lw[3]};
    ((ushort4*)hi)[i] = hv;
    ((ushort4*)lo)[i] = lv;
  }
}

// ---------------------------------------------------------------------------
// out_w * SE-scale -> per-batch (hi, lo) bf16   ( w'[b][n][c] = w[n][c]*s[b][c] )
// ---------------------------------------------------------------------------
__global__ __launch_bounds__(256) void scale_w_kernel(
    const float* __restrict__ out_w, const float* __restrict__ scalebuf,
    ushort* __restrict__ hi, ushort* __restrict__ lo)
{
  const int i = blockIdx.x * 256 + threadIdx.x;   // 131072 = 2 * 65536 float4
  const int b = i >> 16, iw = i & 65535, c4 = i & 127;
  float4 v = ((const float4*)out_w)[iw];
  float4 s = ((const float4*)scalebuf)[b * 128 + c4];
  float vv[4] = {v.x * s.x, v.y * s.y, v.z * s.z, v.w * s.w};
  ushort h[4], lw[4];
#pragma unroll
  for (int j = 0; j < 4; j++) {
    ushort hb = bf16_rne(vv[j]);
    h[j] = hb;
    lw[j] = bf16_rne(vv[j] - bf2f(hb));
  }
  ushort4 hv = {h[0], h[1], h[2], h[3]};
  ushort4 lv = {lw[0], lw[1], lw[2], lw[3]};
  ((ushort4*)hi)[i] = hv;
  ((ushort4*)lo)[i] = lv;
}

// ---------------------------------------------------------------------------
// MFMA GEMM (hi/lo split, fp32-equivalent): C[m,n] = sum_k A[m,k] * B[n,k]
// 128x128 tile, BK=32, 4 waves (2x2), 4x4 fragments of 16x16x32, 3 MFMA each.
// MODE 0: N=1024 -> cols <512 to Ck (+bk), >=512 to Cv (+bv)
// MODE 1: N=512, B has per-batch offset (m0>>12)*2^18 -> silu -> Ck
// ---------------------------------------------------------------------------
template<int MODE>
__global__ __launch_bounds__(256, 2) void gemm_mfma(
    const ushort* __restrict__ Ahi, const ushort* __restrict__ Alo,
    const ushort* __restrict__ Bhi, const ushort* __restrict__ Blo,
    const float* __restrict__ bk, const float* __restrict__ bv,
    float* __restrict__ Ck, float* __restrict__ Cv)
{
  __shared__ ushort smem[4 * 4096];   // Ahi | Alo | Bhi | Blo tiles (128x32 each)
  const int t   = threadIdx.x;
  const int wid = t >> 6, l = t & 63;
  const int m0  = blockIdx.x * 128;
  const int n0  = blockIdx.y * 128;

  const ushort* Bh = Bhi;
  const ushort* Bl = Blo;
  if (MODE == 1) {
    size_t off = (size_t)(m0 >> 12) << 18;   // batch * 512*512
    Bh += off; Bl += off;
  }

  // staging pointers: 8 x global_load_lds(16B) per K-step
  const ushort* gsrc[8];
  uint32_t loff[8];
  {
    const ushort* mp[4] = {Ahi, Alo, Bh, Bl};
#pragma unroll
    for (int mat = 0; mat < 4; mat++) {
      int base = (mat < 2) ? m0 : n0;
#pragma unroll
      for (int i = 0; i < 2; i++) {
        int r = base + i * 64 + (t >> 2);
        gsrc[mat * 2 + i] = mp[mat] + (size_t)r * 512 + (t & 3) * 8;
        loff[mat * 2 + i] = mat * 4096 + i * 2048 + wid * 512;  // wave-uniform
      }
    }
  }

  f32x4 acc[4][4];
#pragma unroll
  for (int m = 0; m < 4; m++)
#pragma unroll
    for (int n = 0; n < 4; n++) acc[m][n] = (f32x4){0.f, 0.f, 0.f, 0.f};

  const int wr = wid >> 1, wc = wid & 1;
  const int fr = l & 15, fk = l >> 4;
  const int aoff = (wr * 64 + fr) * 32 + fk * 8;   // ushort index, + m*512
  const int boff = (wc * 64 + fr) * 32 + fk * 8;   // ushort index, + n*512

  for (int k0 = 0; k0 < 512; k0 += 32) {
#pragma unroll
    for (int j = 0; j < 8; j++) {
      gload_lds16(gsrc[j], &smem[loff[j]]);
      gsrc[j] += 32;
    }
    __syncthreads();   // drains vmcnt -> tiles resident

    bf16x8 ah[4], al[4], bh[4], bl[4];
#pragma unroll
    for (int m = 0; m < 4; m++) {
      ah[m] = *(const bf16x8*)&smem[0 * 4096 + aoff + m * 512];
      al[m] = *(const bf16x8*)&smem[1 * 4096 + aoff + m * 512];
    }
#pragma unroll
    for (int n = 0; n < 4; n++) {
      bh[n] = *(const bf16x8*)&smem[2 * 4096 + boff + n * 512];
      bl[n] = *(const bf16x8*)&smem[3 * 4096 + boff + n * 512];
    }
#pragma unroll
    for (int m = 0; m < 4; m++)
#pragma unroll
      for (int n = 0; n < 4; n++) {
        acc[m][n] = __builtin_amdgcn_mfma_f32_16x16x32_bf16(ah[m], bh[n], acc[m][n], 0, 0, 0);
        acc[m][n] = __builtin_amdgcn_mfma_f32_16x16x32_bf16(ah[m], bl[n], acc[m][n], 0, 0, 0);
        acc[m][n] = __builtin_amdgcn_mfma_f32_16x16x32_bf16(al[m], bh[n], acc[m][n], 0, 0, 0);
      }
    __syncthreads();   // all reads done before next stage overwrites
  }

  // epilogue: C/D layout col=lane&15, row=(lane>>4)*4+reg  [m89/m91]
  const int rbase = m0 + wr * 64 + (l >> 4) * 4;
  const int cbase = n0 + wc * 64 + (l & 15);
#pragma unroll
  for (int m = 0; m < 4; m++)
#pragma unroll
    for (int n = 0; n < 4; n++) {
      const int c = cbase + n * 16;
#pragma unroll
      for (int j = 0; j < 4; j++) {
        const int r = rbase + m * 16 + j;
        float v = acc[m][n][j];
        if (MODE == 0) {
          if (n0 < 512) Ck[(size_t)r * 512 + c] = v + bk[c];
          else          Cv[(size_t)r * 512 + (c - 512)] = v + bv[c - 512];
        } else {
          Ck[(size_t)r * 512 + c] = v / (1.f + expf(-v));
        }
      }
    }
}

// ---------------------------------------------------------------------------
// window / offset projection (N=16 skinny) + rmsnorm(H=8) + sigmoid/tanh
// ALSO: writes the x hi/lo bf16 split (x already resident per row)
// ---------------------------------------------------------------------------
__global__ __launch_bounds__(256) void winoff_kernel(
    const float* __restrict__ x,
    const float* __restrict__ window_w, const float* __restrict__ window_b,
    const float* __restrict__ window_g,
    const float* __restrict__ offset_w, const float* __restrict__ offset_b,
    const float* __restrict__ offset_g,
    float* __restrict__ halfwin, float* __restrict__ cenoff,
    ushort* __restrict__ xhi, ushort* __restrict__ xlo)
{
  __shared__ float wsm[16][512];   // rows 0..7 window_w, 8..15 offset_w
  const int t = threadIdx.x;
  {
    float4* dst = (float4*)&wsm[0][0];
    for (int i = t; i < 2048; i += 256)
      dst[i] = (i < 1024) ? ((const float4*)window_w)[i] : ((const float4*)offset_w)[i - 1024];
  }
  __syncthreads();
  const int wid = t >> 6, lane = t & 63;
  for (int it = 0; it < 4; it++) {
    const int row = blockIdx.x * 16 + it * 4 + wid;
    const float* xr = x + (size_t)row * 512;
    float xv[8];
#pragma unroll
    for (int j = 0; j < 8; j++) xv[j] = xr[lane + j * 64];
    // emit hi/lo bf16 split of this row
#pragma unroll
    for (int j = 0; j < 8; j++) {
      ushort hb = bf16_rne(xv[j]);
      xhi[(size_t)row * 512 + lane + j * 64] = hb;
      xlo[(size_t)row * 512 + lane + j * 64] = bf16_rne(xv[j] - bf2f(hb));
    }
    float s[16];
#pragma unroll
    for (int n = 0; n < 16; n++) {
      float p = 0.f;
#pragma unroll
      for (int j = 0; j < 8; j++) p += xv[j] * wsm[n][lane + j * 64];
#pragma unroll
      for (int off = 32; off >= 1; off >>= 1) p += __shfl_xor(p, off);
      s[n] = p;
    }
    float ssw = 0.f, sso = 0.f;
#pragma unroll
    for (int h = 0; h < 8; h++) {
      s[h]     += window_b[h]; ssw += s[h] * s[h];
      s[8 + h] += offset_b[h]; sso += s[8 + h] * s[8 + h];
    }
    float rw = rsqrtf(ssw * 0.125f + 1e-6f);
    float ro = rsqrtf(sso * 0.125f + 1e-6f);
    if (lane < 8) {
      float z  = window_g[lane] * s[lane] * rw;
      float wr2 = 1.f / (1.f + expf(-z));
      halfwin[(size_t)row * 8 + lane] = fmaxf((1.0f + wr2 * 11.0f) * 0.5f, 0.5f);
    } else if (lane < 16) {
      int h = lane - 8;
      float z = offset_g[h] * s[8 + h] * ro;
      cenoff[(size_t)row * 8 + h] = tanhf(z) * 12.0f;
    }
  }
}

// ---------------------------------------------------------------------------
// rmsnorm over 512 + silu, in place (kernel projection)
// ---------------------------------------------------------------------------
__global__ __launch_bounds__(256) void rms_silu_kernel(
    float* __restrict__ kact, const float* __restrict__ gamma)
{
  const int row = blockIdx.x;
  const int t = threadIdx.x;
  float* kr = kact + (size_t)row * 512;
  float v0 = kr[t], v1 = kr[t + 256];
  float ss = v0 * v0 + v1 * v1;
#pragma unroll
  for (int off = 32; off >= 1; off >>= 1) ss += __shfl_xor(ss, off);
  __shared__ float red[4];
  const int wid = t >> 6, lane = t & 63;
  if (lane == 0) red[wid] = ss;
  __syncthreads();
  float tot = red[0] + red[1] + red[2] + red[3];
  float r = rsqrtf(tot * (1.f / 512.f) + 1e-6f);
  float a0 = gamma[t] * v0 * r;
  float a1 = gamma[t + 256] * v1 * r;
  kr[t]       = a0 / (1.f + expf(-a0));
  kr[t + 256] = a1 / (1.f + expf(-a1));
}

// ---------------------------------------------------------------------------
// deformable local conv: wave per (row, h), lane per d (D=64)
// ---------------------------------------------------------------------------
__global__ __launch_bounds__(256) void conv_kernel(
    const float* __restrict__ halfwin, const float* __restrict__ cenoff,
    const float* __restrict__ kact, const float* __restrict__ vbuf,
    ushort* __restrict__ oh_hi, ushort* __restrict__ oh_lo)
{
  const int wid = threadIdx.x >> 6, lane = threadIdx.x & 63;
  const int gw  = blockIdx.x * 4 + wid;     // 0 .. BL*H-1
  const int row = gw >> 3, h = gw & 7;
  const int b   = row >> 12, l = row & 4095;
  const float hw = halfwin[gw];
  const float co = cenoff[gw];
  const float* kr = kact + (size_t)row * 512 + h * 64;
  const float* vbase = vbuf + ((size_t)b * 4096) * 512 + h * 64;  // + pf*512 + lane

  // weight phase: lane si in [0,13)
  float w = 0.f, frv = 0.f;
  int pfv = 0;
  if (lane < 13) {
    const int soff = lane - 6;
    float rel  = fabsf((float)soff) / hw;
    float ww   = __expf(-rel * rel);
    float npos = fminf(rel, 1.f) * 63.f;
    int   idx  = min((int)npos, 62);
    float wc   = npos - (float)idx;
    float kf = kr[idx], kc = kr[idx + 1];
    float kw = fmaxf(kf * (1.f - wc) + kc * wc, 0.f);
    float nb = (float)l + co + (float)soff;
    w = (nb >= 0.f && nb < 4096.f) ? (kw + 1.f) * ww : 0.f;
    float pc = fminf(fmaxf(nb, 0.f), 4094.999f);
    pfv = (int)pc;
    frv = pc - (float)pfv;
  }
  float wsum = w;
#pragma unroll
  for (int off = 32; off >= 1; off >>= 1) wsum += __shfl_xor(wsum, off);

  float acc = 0.f;
#pragma unroll
  for (int si = 0; si < 13; si++) {
    const float w_s  = readlane_f(w, si);
    const float fr_s = readlane_f(frv, si);
    const int   pf_s = __builtin_amdgcn_readlane(pfv, si);
    const float* vrow = vbase + (size_t)pf_s * 512;   // uniform -> SGPR base
    float v0 = vrow[lane];
    float v1 = vrow[lane + 512];                      // pf_s <= 4094 always
    float t0 = v0 + fr_s * (v1 - v0);
    acc = fmaf(w_s, t0, acc);
  }

  float val = acc / fmaxf(wsum, 1.f);
  ushort hb = bf16_rne(val);
  ushort lb = bf16_rne(val - bf2f(hb));
  oh_hi[(size_t)row * 512 + h * 64 + lane] = hb;
  oh_lo[(size_t)row * 512 + h * 64 + lane] = lb;
}

// ---------------------------------------------------------------------------
// column partial sums over L chunks (for the SE mean), reads hi/lo bf16
// ---------------------------------------------------------------------------
__global__ __launch_bounds__(256) void colpart_kernel(
    const ushort* __restrict__ oh_hi, const ushort* __restrict__ oh_lo,
    float* __restrict__ partial)
{
  const int blk = blockIdx.x;               // B*32
  const int b = blk >> 5, chunk = blk & 31;
  const int t = threadIdx.x;
  const size_t base = ((size_t)b * 4096 + (size_t)chunk * 128) * 512;
  float s0 = 0.f, s1 = 0.f;
  for (int i = 0; i < 128; i++) {
    const size_t o = base + (size_t)i * 512;
    s0 += bf2f(oh_hi[o + t])       + bf2f(oh_lo[o + t]);
    s1 += bf2f(oh_hi[o + 256 + t]) + bf2f(oh_lo[o + 256 + t]);
  }
  partial[(size_t)blk * 512 + t]       = s0;
  partial[(size_t)blk * 512 + 256 + t] = s1;
}

// ---------------------------------------------------------------------------
// SE stage 1: mean over chunks  -> mean_g (2,512)
// ---------------------------------------------------------------------------
__global__ __launch_bounds__(512) void se_mean_kernel(
    const float* __restrict__ partial, float* __restrict__ mean_g)
{
  const int b = blockIdx.x, c = threadIdx.x;
  float m = 0.f;
#pragma unroll
  for (int ch = 0; ch < 32; ch++) m += partial[(size_t)(b * 32 + ch) * 512 + c];
  mean_g[b * 512 + c] = m * (1.f / 4096.f);
}

// ---------------------------------------------------------------------------
// SE stage 2: hid = silu(mean @ w1^T)   wave per (b, j) output, 256 waves
// ---------------------------------------------------------------------------
__global__ __launch_bounds__(256) void se_hid_kernel(
    const float* __restrict__ mean_g, const float* __restrict__ w1,
    float* __restrict__ hid_g)
{
  const int wid = threadIdx.x >> 6, lane = threadIdx.x & 63;
  const int g = blockIdx.x * 4 + wid;       // 0..255
  const int b2 = g >> 7, j = g & 127;
  float4 wv0 = ((const float4*)(w1 + (size_t)j * 512))[lane * 2];
  float4 wv1 = ((const float4*)(w1 + (size_t)j * 512))[lane * 2 + 1];
  float4 mv0 = ((const float4*)(mean_g + b2 * 512))[lane * 2];
  float4 mv1 = ((const float4*)(mean_g + b2 * 512))[lane * 2 + 1];
  float p = wv0.x * mv0.x + wv0.y * mv0.y + wv0.z * mv0.z + wv0.w * mv0.w
          + wv1.x * mv1.x + wv1.y * mv1.y + wv1.z * mv1.z + wv1.w * mv1.w;
#pragma unroll
  for (int off = 32; off >= 1; off >>= 1) p += __shfl_xor(p, off);
  if (lane == 0) hid_g[g] = p / (1.f + expf(-p));
}

// ---------------------------------------------------------------------------
// SE stage 3: scale = sigmoid(hid @ w2^T)   wave per (b, c) output, 1024 waves
// ---------------------------------------------------------------------------
__global__ __launch_bounds__(256) void se_scale_kernel(
    const float* __restrict__ hid_g, const float* __restrict__ w2,
    float* __restrict__ scalebuf)
{
  const int wid = threadIdx.x >> 6, lane = threadIdx.x & 63;
  const int g = blockIdx.x * 4 + wid;       // 0..1023
  const int b3 = g >> 9, c = g & 511;
  float2 wv = ((const float2*)(w2 + (size_t)c * 128))[lane];
  float2 hv = ((const float2*)(hid_g + b3 * 128))[lane];
  float p = wv.x * hv.x + wv.y * hv.y;
#pragma unroll
  for (int off = 32; off >= 1; off >>= 1) p += __shfl_xor(p, off);
  if (lane == 0) scalebuf[g] = 1.f / (1.f + expf(-p));
}

// ---------------------------------------------------------------------------
extern "C" void kernel_launch(void* const* d_in, const int* in_sizes, int n_in,
                              void* d_out, int out_size, void* d_ws, size_t ws_size,
                              hipStream_t stream) {
  const float* x        = (const float*)d_in[0];
  const float* window_w = (const float*)d_in[1];
  const float* window_b = (const float*)d_in[2];
  const float* window_g = (const float*)d_in[3];
  const float* offset_w = (const float*)d_in[4];
  const float* offset_b = (const float*)d_in[5];
  const float* offset_g = (const float*)d_in[6];
  const float* kernel_w = (const float*)d_in[7];
  const float* kernel_b = (const float*)d_in[8];
  const float* kernel_g = (const float*)d_in[9];
  const float* v_w      = (const float*)d_in[10];
  const float* v_b      = (const float*)d_in[11];
  const float* se_w1    = (const float*)d_in[12];
  const float* se_w2    = (const float*)d_in[13];
  const float* out_w    = (const float*)d_in[14];
  float* out = (float*)d_out;
  char* ws   = (char*)d_ws;

  const size_t BLC = (size_t)8192 * 512;
  float* kact     = (float*)ws;                       ws += BLC * 4;   // (BL,512)
  float* vbuf     = (float*)ws;                       ws += BLC * 4;   // (BL,512)
  float* halfwin  = (float*)ws;                       ws += 65536 * 4;
  float* cenoff   = (float*)ws;                       ws += 65536 * 4;
  float* partial  = (float*)ws;                       ws += 64 * 512 * 4;
  float* mean_g   = (float*)ws;                       ws += 1024 * 4;
  float* hid_g    = (float*)ws;                       ws += 256 * 4;
  float* scalebuf = (float*)ws;                       ws += 1024 * 4;
  ushort* xhi     = (ushort*)ws;                      ws += BLC * 2;
  ushort* xlo     = (ushort*)ws;                      ws += BLC * 2;
  ushort* wkvhi   = (ushort*)ws;                      ws += 1024 * 512 * 2;
  ushort* wkvlo   = (ushort*)ws;                      ws += 1024 * 512 * 2;
  ushort* oh_hi   = (ushort*)ws;                      ws += BLC * 2;
  ushort* oh_lo   = (ushort*)ws;                      ws += BLC * 2;
  ushort* owshi   = (ushort*)ws;                      ws += 2 * 512 * 512 * 2;
  ushort* owslo   = (ushort*)ws;                      ws += 2 * 512 * 512 * 2;

  // 1. window/offset projection + x hi/lo split (x read once)
  winoff_kernel<<<512, 256, 0, stream>>>(x, window_w, window_b, window_g,
                                         offset_w, offset_b, offset_g,
                                         halfwin, cenoff, xhi, xlo);
  // 0. weight hi/lo conversions
  split_bf16<<<256, 256, 0, stream>>>(kernel_w, wkvhi, wkvlo, 65536);
  split_bf16<<<256, 256, 0, stream>>>(v_w, wkvhi + 262144, wkvlo + 262144, 65536);

  // 2. kernel + v projections (fused dual MFMA GEMM over N=1024)
  gemm_mfma<0><<<dim3(64, 8), 256, 0, stream>>>(xhi, xlo, wkvhi, wkvlo,
                                                kernel_b, v_b, kact, vbuf);
  // 3. rmsnorm + silu on kernel projection
  rms_silu_kernel<<<8192, 256, 0, stream>>>(kact, kernel_g);
  // 4. deformable conv -> hi/lo bf16 output
  conv_kernel<<<16384, 256, 0, stream>>>(halfwin, cenoff, kact, vbuf, oh_hi, oh_lo);
  // 5. SE path (parallel-shaped)
  colpart_kernel<<<64, 256, 0, stream>>>(oh_hi, oh_lo, partial);
  se_mean_kernel<<<2, 512, 0, stream>>>(partial, mean_g);
  se_hid_kernel<<<64, 256, 0, stream>>>(mean_g, se_w1, hid_g);
  se_scale_kernel<<<256, 256, 0, stream>>>(hid_g, se_w2, scalebuf);
  // 6. fold SE scale into out_w (per batch), split to bf16
  scale_w_kernel<<<512, 256, 0, stream>>>(out_w, scalebuf, owshi, owslo);
  // 7. final MFMA GEMM + silu (A = conv output hi/lo, B = scaled out_w)
  gemm_mfma<1><<<dim3(64, 4), 256, 0, stream>>>(oh_hi, oh_lo, owshi, owslo,
                                                nullptr, nullptr, out, nullptr);
}

// Round 5
// 125.740 us; speedup vs baseline: 2.5028x; 1.0579x over previous
//
#include <hip/hip_runtime.h>
#include <hip/hip_bf16.h>
#include <cstddef>
#include <cstdint>

// Problem constants (B=2, L=4096, C=512, H=8, K=64, D=64)
// max_window = 12, half_max = 6, S = 13, max_offset = 12.0, hid = 128

typedef short bf16x8 __attribute__((ext_vector_type(8)));
typedef float f32x4 __attribute__((ext_vector_type(4)));

#define AS1 __attribute__((address_space(1)))
#define AS3 __attribute__((address_space(3)))

__device__ __forceinline__ void gload_lds16(const ushort* g, ushort* l) {
  __builtin_amdgcn_global_load_lds((const AS1 uint32_t*)g, (AS3 uint32_t*)l, 16, 0, 0);
}

__device__ __forceinline__ ushort bf16_rne(float x) {
  uint32_t u = __float_as_uint(x);
  return (ushort)((u + 0x7fffu + ((u >> 16) & 1u)) >> 16);
}
__device__ __forceinline__ float bf2f(ushort u) {
  return __uint_as_float(((uint32_t)u) << 16);
}
__device__ __forceinline__ float readlane_f(float v, int l) {
  return __int_as_float(__builtin_amdgcn_readlane(__float_as_int(v), l));
}

// ---------------------------------------------------------------------------
// fp32 -> (hi, lo) bf16 split, vectorized float4  (weights only)
// ---------------------------------------------------------------------------
__global__ __launch_bounds__(256) void split_bf16(
    const float* __restrict__ src, ushort* __restrict__ hi,
    ushort* __restrict__ lo, int n4)
{
  for (int i = blockIdx.x * 256 + threadIdx.x; i < n4; i += gridDim.x * 256) {
    float4 v = ((const float4*)src)[i];
    float vv[4] = {v.x, v.y, v.z, v.w};
    ushort h[4], lw[4];
#pragma unroll
    for (int j = 0; j < 4; j++) {
      ushort hb = bf16_rne(vv[j]);
      h[j] = hb;
      lw[j] = bf16_rne(vv[j] - bf2f(hb));
    }
    ushort4 hv = {h[0], h[1], h[2], h[3]};
    ushort4 lv = {lw[0], lw[1], lw[2], lw[3]};
    ((ushort4*)hi)[i] = hv;
    ((ushort4*)lo)[i] = lv;
  }
}

// ---------------------------------------------------------------------------
// out_w * SE-scale -> per-batch (hi, lo) bf16   ( w'[b][n][c] = w[n][c]*s[b][c] )
// ---------------------------------------------------------------------------
__global__ __launch_bounds__(256) void scale_w_kernel(
    const float* __restrict__ out_w, const float* __restrict__ scalebuf,
    ushort* __restrict__ hi, ushort* __restrict__ lo)
{
  const int i = blockIdx.x * 256 + threadIdx.x;   // 131072 = 2 * 65536 float4
  const int b = i >> 16, iw = i & 65535, c4 = i & 127;
  float4 v = ((const float4*)out_w)[iw];
  float4 s = ((const float4*)scalebuf)[b * 128 + c4];
  float vv[4] = {v.x * s.x, v.y * s.y, v.z * s.z, v.w * s.w};
  ushort h[4], lw[4];
#pragma unroll
  for (int j = 0; j < 4; j++) {
    ushort hb = bf16_rne(vv[j]);
    h[j] = hb;
    lw[j] = bf16_rne(vv[j] - bf2f(hb));
  }
  ushort4 hv = {h[0], h[1], h[2], h[3]};
  ushort4 lv = {lw[0], lw[1], lw[2], lw[3]};
  ((ushort4*)hi)[i] = hv;
  ((ushort4*)lo)[i] = lv;
}

// ---------------------------------------------------------------------------
// MFMA GEMM (hi/lo split, fp32-equivalent): C[m,n] = sum_k A[m,k] * B[n,k]
// 128x128 tile, BK=32, 4 waves (2x2), 4x4 fragments of 16x16x32, 3 MFMA each.
// 1D grid + XCD-chunked swizzle (8 bx-tiles per XCD stripe -> L2-resident panels)
// MODE 0: 512 blocks (64x8), N=1024 -> cols <512 to Ck (+bk), >=512 to Cv (+bv)
// MODE 1: 256 blocks (64x4), N=512, B per-batch offset -> silu -> Ck
// ---------------------------------------------------------------------------
template<int MODE>
__global__ __launch_bounds__(256, 2) void gemm_mfma(
    const ushort* __restrict__ Ahi, const ushort* __restrict__ Alo,
    const ushort* __restrict__ Bhi, const ushort* __restrict__ Blo,
    const float* __restrict__ bk, const float* __restrict__ bv,
    float* __restrict__ Ck, float* __restrict__ Cv)
{
  __shared__ ushort smem[4 * 4096];   // Ahi | Alo | Bhi | Blo tiles (128x32 each)
  const int t   = threadIdx.x;
  const int wid = t >> 6, l = t & 63;

  // XCD swizzle: bid%8 ~ XCD; each XCD owns an 8-tile bx stripe, all by.
  const int bid = blockIdx.x;
  const int xcd = bid & 7, idx = bid >> 3;
  const int bx = (xcd << 3) | (idx & 7);
  const int by = idx >> 3;
  const int m0 = bx * 128;
  const int n0 = by * 128;

  const ushort* Bh = Bhi;
  const ushort* Bl = Blo;
  if (MODE == 1) {
    size_t off = (size_t)(m0 >> 12) << 18;   // batch * 512*512
    Bh += off; Bl += off;
  }

  // staging pointers: 8 x global_load_lds(16B) per K-step
  const ushort* gsrc[8];
  uint32_t loff[8];
  {
    const ushort* mp[4] = {Ahi, Alo, Bh, Bl};
#pragma unroll
    for (int mat = 0; mat < 4; mat++) {
      int base = (mat < 2) ? m0 : n0;
#pragma unroll
      for (int i = 0; i < 2; i++) {
        int r = base + i * 64 + (t >> 2);
        gsrc[mat * 2 + i] = mp[mat] + (size_t)r * 512 + (t & 3) * 8;
        loff[mat * 2 + i] = mat * 4096 + i * 2048 + wid * 512;  // wave-uniform
      }
    }
  }

  f32x4 acc[4][4];
#pragma unroll
  for (int m = 0; m < 4; m++)
#pragma unroll
    for (int n = 0; n < 4; n++) acc[m][n] = (f32x4){0.f, 0.f, 0.f, 0.f};

  const int wr = wid >> 1, wc = wid & 1;
  const int fr = l & 15, fk = l >> 4;
  const int aoff = (wr * 64 + fr) * 32 + fk * 8;   // ushort index, + m*512
  const int boff = (wc * 64 + fr) * 32 + fk * 8;   // ushort index, + n*512

  for (int k0 = 0; k0 < 512; k0 += 32) {
#pragma unroll
    for (int j = 0; j < 8; j++) {
      gload_lds16(gsrc[j], &smem[loff[j]]);
      gsrc[j] += 32;
    }
    __syncthreads();   // drains vmcnt -> tiles resident

    bf16x8 ah[4], al[4], bh[4], bl[4];
#pragma unroll
    for (int m = 0; m < 4; m++) {
      ah[m] = *(const bf16x8*)&smem[0 * 4096 + aoff + m * 512];
      al[m] = *(const bf16x8*)&smem[1 * 4096 + aoff + m * 512];
    }
#pragma unroll
    for (int n = 0; n < 4; n++) {
      bh[n] = *(const bf16x8*)&smem[2 * 4096 + boff + n * 512];
      bl[n] = *(const bf16x8*)&smem[3 * 4096 + boff + n * 512];
    }
#pragma unroll
    for (int m = 0; m < 4; m++)
#pragma unroll
      for (int n = 0; n < 4; n++) {
        acc[m][n] = __builtin_amdgcn_mfma_f32_16x16x32_bf16(ah[m], bh[n], acc[m][n], 0, 0, 0);
        acc[m][n] = __builtin_amdgcn_mfma_f32_16x16x32_bf16(ah[m], bl[n], acc[m][n], 0, 0, 0);
        acc[m][n] = __builtin_amdgcn_mfma_f32_16x16x32_bf16(al[m], bh[n], acc[m][n], 0, 0, 0);
      }
    __syncthreads();   // all reads done before next stage overwrites
  }

  // epilogue: C/D layout col=lane&15, row=(lane>>4)*4+reg  [m89/m91]
  const int rbase = m0 + wr * 64 + (l >> 4) * 4;
  const int cbase = n0 + wc * 64 + (l & 15);
#pragma unroll
  for (int m = 0; m < 4; m++)
#pragma unroll
    for (int n = 0; n < 4; n++) {
      const int c = cbase + n * 16;
#pragma unroll
      for (int j = 0; j < 4; j++) {
        const int r = rbase + m * 16 + j;
        float v = acc[m][n][j];
        if (MODE == 0) {
          if (n0 < 512) Ck[(size_t)r * 512 + c] = v + bk[c];
          else          Cv[(size_t)r * 512 + (c - 512)] = v + bv[c - 512];
        } else {
          Ck[(size_t)r * 512 + c] = v / (1.f + expf(-v));
        }
      }
    }
}

// ---------------------------------------------------------------------------
// window / offset projection (N=16 skinny) + rmsnorm(H=8) + sigmoid/tanh
// ALSO: writes the x hi/lo bf16 split (x already resident per row)
// ---------------------------------------------------------------------------
__global__ __launch_bounds__(256) void winoff_kernel(
    const float* __restrict__ x,
    const float* __restrict__ window_w, const float* __restrict__ window_b,
    const float* __restrict__ window_g,
    const float* __restrict__ offset_w, const float* __restrict__ offset_b,
    const float* __restrict__ offset_g,
    float* __restrict__ halfwin, float* __restrict__ cenoff,
    ushort* __restrict__ xhi, ushort* __restrict__ xlo)
{
  __shared__ float wsm[16][512];   // rows 0..7 window_w, 8..15 offset_w
  const int t = threadIdx.x;
  {
    float4* dst = (float4*)&wsm[0][0];
    for (int i = t; i < 2048; i += 256)
      dst[i] = (i < 1024) ? ((const float4*)window_w)[i] : ((const float4*)offset_w)[i - 1024];
  }
  __syncthreads();
  const int wid = t >> 6, lane = t & 63;
  for (int it = 0; it < 4; it++) {
    const int row = blockIdx.x * 16 + it * 4 + wid;
    const float* xr = x + (size_t)row * 512;
    float xv[8];
#pragma unroll
    for (int j = 0; j < 8; j++) xv[j] = xr[lane + j * 64];
    // emit hi/lo bf16 split of this row
#pragma unroll
    for (int j = 0; j < 8; j++) {
      ushort hb = bf16_rne(xv[j]);
      xhi[(size_t)row * 512 + lane + j * 64] = hb;
      xlo[(size_t)row * 512 + lane + j * 64] = bf16_rne(xv[j] - bf2f(hb));
    }
    float s[16];
#pragma unroll
    for (int n = 0; n < 16; n++) {
      float p = 0.f;
#pragma unroll
      for (int j = 0; j < 8; j++) p += xv[j] * wsm[n][lane + j * 64];
#pragma unroll
      for (int off = 32; off >= 1; off >>= 1) p += __shfl_xor(p, off);
      s[n] = p;
    }
    float ssw = 0.f, sso = 0.f;
#pragma unroll
    for (int h = 0; h < 8; h++) {
      s[h]     += window_b[h]; ssw += s[h] * s[h];
      s[8 + h] += offset_b[h]; sso += s[8 + h] * s[8 + h];
    }
    float rw = rsqrtf(ssw * 0.125f + 1e-6f);
    float ro = rsqrtf(sso * 0.125f + 1e-6f);
    if (lane < 8) {
      float z  = window_g[lane] * s[lane] * rw;
      float wr2 = 1.f / (1.f + expf(-z));
      halfwin[(size_t)row * 8 + lane] = fmaxf((1.0f + wr2 * 11.0f) * 0.5f, 0.5f);
    } else if (lane < 16) {
      int h = lane - 8;
      float z = offset_g[h] * s[8 + h] * ro;
      cenoff[(size_t)row * 8 + h] = tanhf(z) * 12.0f;
    }
  }
}

// ---------------------------------------------------------------------------
// fused rmsnorm+silu + deformable conv: one block = one row (512 thr, 8 waves)
// wave w handles head h=w, lane per d. kact row activated in LDS.
// XCD-chunked row swizzle -> v gather window L2-resident per XCD.
// ---------------------------------------------------------------------------
__global__ __launch_bounds__(512) void conv_row_kernel(
    const float* __restrict__ halfwin, const float* __restrict__ cenoff,
    const float* __restrict__ kact_raw, const float* __restrict__ kernel_g,
    const float* __restrict__ vbuf,
    ushort* __restrict__ oh_hi, ushort* __restrict__ oh_lo)
{
  __shared__ float kn[512];
  __shared__ float red[8];
  const int bid = blockIdx.x;                       // 8192
  const int row = ((bid & 7) << 10) | (bid >> 3);   // XCD chunk: 1024 rows/XCD
  const int t = threadIdx.x, w = t >> 6, lane = t & 63;
  const int b = row >> 12, l = row & 4095;

  // rmsnorm + silu on kact row (in LDS)
  float kraw = kact_raw[(size_t)row * 512 + t];
  float ss = kraw * kraw;
#pragma unroll
  for (int off = 32; off >= 1; off >>= 1) ss += __shfl_xor(ss, off);
  if (lane == 0) red[w] = ss;
  __syncthreads();
  float tot = red[0] + red[1] + red[2] + red[3]
            + red[4] + red[5] + red[6] + red[7];
  float r = rsqrtf(tot * (1.f / 512.f) + 1e-6f);
  float a = kernel_g[t] * kraw * r;
  kn[t] = a / (1.f + expf(-a));
  __syncthreads();

  const int gw = row * 8 + w;
  const float hw = halfwin[gw];
  const float co = cenoff[gw];
  const float* vbase = vbuf + ((size_t)b * 4096) * 512 + w * 64;  // + pf*512 + lane

  // weight phase: lane si in [0,13)
  float wgt = 0.f, frv = 0.f;
  int pfv = 0;
  if (lane < 13) {
    const int soff = lane - 6;
    float rel  = fabsf((float)soff) / hw;
    float ww   = __expf(-rel * rel);
    float npos = fminf(rel, 1.f) * 63.f;
    int   idx  = min((int)npos, 62);
    float wc   = npos - (float)idx;
    float kf = kn[w * 64 + idx], kc = kn[w * 64 + idx + 1];
    float kw = fmaxf(kf * (1.f - wc) + kc * wc, 0.f);
    float nb = (float)l + co + (float)soff;
    wgt = (nb >= 0.f && nb < 4096.f) ? (kw + 1.f) * ww : 0.f;
    float pc = fminf(fmaxf(nb, 0.f), 4094.999f);
    pfv = (int)pc;
    frv = pc - (float)pfv;
  }
  float wsum = wgt;
#pragma unroll
  for (int off = 32; off >= 1; off >>= 1) wsum += __shfl_xor(wsum, off);

  float acc = 0.f;
#pragma unroll
  for (int si = 0; si < 13; si++) {
    const float w_s  = readlane_f(wgt, si);
    const float fr_s = readlane_f(frv, si);
    const int   pf_s = __builtin_amdgcn_readlane(pfv, si);
    const float* vrow = vbase + (size_t)pf_s * 512;   // uniform -> SGPR base
    float v0 = vrow[lane];
    float v1 = vrow[lane + 512];                      // pf_s <= 4094 always
    float t0 = v0 + fr_s * (v1 - v0);
    acc = fmaf(w_s, t0, acc);
  }

  float val = acc / fmaxf(wsum, 1.f);
  ushort hb = bf16_rne(val);
  ushort lb = bf16_rne(val - bf2f(hb));
  oh_hi[(size_t)row * 512 + w * 64 + lane] = hb;
  oh_lo[(size_t)row * 512 + w * 64 + lane] = lb;
}

// ---------------------------------------------------------------------------
// column partial sums over L chunks (for the SE mean), reads hi bf16 only
// ---------------------------------------------------------------------------
__global__ __launch_bounds__(256) void colpart_kernel(
    const ushort* __restrict__ oh_hi, float* __restrict__ partial)
{
  const int blk = blockIdx.x;               // B*32
  const int b = blk >> 5, chunk = blk & 31;
  const int t = threadIdx.x;
  const size_t base = ((size_t)b * 4096 + (size_t)chunk * 128) * 512;
  float s0 = 0.f, s1 = 0.f;
  for (int i = 0; i < 128; i++) {
    const size_t o = base + (size_t)i * 512;
    s0 += bf2f(oh_hi[o + t]);
    s1 += bf2f(oh_hi[o + 256 + t]);
  }
  partial[(size_t)blk * 512 + t]       = s0;
  partial[(size_t)blk * 512 + 256 + t] = s1;
}

// ---------------------------------------------------------------------------
// SE stage 1+2 fused: mean inline, hid = silu(mean @ w1^T); wave per (b,j)
// ---------------------------------------------------------------------------
__global__ __launch_bounds__(256) void se_hid_kernel(
    const float* __restrict__ partial, const float* __restrict__ w1,
    float* __restrict__ hid_g)
{
  const int wid = threadIdx.x >> 6, lane = threadIdx.x & 63;
  const int g = blockIdx.x * 4 + wid;       // 0..255
  const int b2 = g >> 7, j = g & 127;
  float4 m0 = {0.f, 0.f, 0.f, 0.f}, m1 = {0.f, 0.f, 0.f, 0.f};
#pragma unroll 8
  for (int ch = 0; ch < 32; ch++) {
    const float4* pr = (const float4*)(partial + (size_t)(b2 * 32 + ch) * 512);
    float4 a0 = pr[lane * 2], a1 = pr[lane * 2 + 1];
    m0.x += a0.x; m0.y += a0.y; m0.z += a0.z; m0.w += a0.w;
    m1.x += a1.x; m1.y += a1.y; m1.z += a1.z; m1.w += a1.w;
  }
  float4 wv0 = ((const float4*)(w1 + (size_t)j * 512))[lane * 2];
  float4 wv1 = ((const float4*)(w1 + (size_t)j * 512))[lane * 2 + 1];
  float p = (wv0.x * m0.x + wv0.y * m0.y + wv0.z * m0.z + wv0.w * m0.w
           + wv1.x * m1.x + wv1.y * m1.y + wv1.z * m1.z + wv1.w * m1.w) * (1.f / 4096.f);
#pragma unroll
  for (int off = 32; off >= 1; off >>= 1) p += __shfl_xor(p, off);
  if (lane == 0) hid_g[g] = p / (1.f + expf(-p));
}

// ---------------------------------------------------------------------------
// SE stage 3: scale = sigmoid(hid @ w2^T)   wave per (b, c) output, 1024 waves
// ---------------------------------------------------------------------------
__global__ __launch_bounds__(256) void se_scale_kernel(
    const float* __restrict__ hid_g, const float* __restrict__ w2,
    float* __restrict__ scalebuf)
{
  const int wid = threadIdx.x >> 6, lane = threadIdx.x & 63;
  const int g = blockIdx.x * 4 + wid;       // 0..1023
  const int b3 = g >> 9, c = g & 511;
  float2 wv = ((const float2*)(w2 + (size_t)c * 128))[lane];
  float2 hv = ((const float2*)(hid_g + b3 * 128))[lane];
  float p = wv.x * hv.x + wv.y * hv.y;
#pragma unroll
  for (int off = 32; off >= 1; off >>= 1) p += __shfl_xor(p, off);
  if (lane == 0) scalebuf[g] = 1.f / (1.f + expf(-p));
}

// ---------------------------------------------------------------------------
extern "C" void kernel_launch(void* const* d_in, const int* in_sizes, int n_in,
                              void* d_out, int out_size, void* d_ws, size_t ws_size,
                              hipStream_t stream) {
  const float* x        = (const float*)d_in[0];
  const float* window_w = (const float*)d_in[1];
  const float* window_b = (const float*)d_in[2];
  const float* window_g = (const float*)d_in[3];
  const float* offset_w = (const float*)d_in[4];
  const float* offset_b = (const float*)d_in[5];
  const float* offset_g = (const float*)d_in[6];
  const float* kernel_w = (const float*)d_in[7];
  const float* kernel_b = (const float*)d_in[8];
  const float* kernel_g = (const float*)d_in[9];
  const float* v_w      = (const float*)d_in[10];
  const float* v_b      = (const float*)d_in[11];
  const float* se_w1    = (const float*)d_in[12];
  const float* se_w2    = (const float*)d_in[13];
  const float* out_w    = (const float*)d_in[14];
  float* out = (float*)d_out;
  char* ws   = (char*)d_ws;

  const size_t BLC = (size_t)8192 * 512;
  float* kact     = (float*)ws;                       ws += BLC * 4;   // raw kernel proj
  float* vbuf     = (float*)ws;                       ws += BLC * 4;
  float* halfwin  = (float*)ws;                       ws += 65536 * 4;
  float* cenoff   = (float*)ws;                       ws += 65536 * 4;
  float* partial  = (float*)ws;                       ws += 64 * 512 * 4;
  float* hid_g    = (float*)ws;                       ws += 256 * 4;
  float* scalebuf = (float*)ws;                       ws += 1024 * 4;
  ushort* xhi     = (ushort*)ws;                      ws += BLC * 2;
  ushort* xlo     = (ushort*)ws;                      ws += BLC * 2;
  ushort* wkvhi   = (ushort*)ws;                      ws += 1024 * 512 * 2;
  ushort* wkvlo   = (ushort*)ws;                      ws += 1024 * 512 * 2;
  ushort* oh_hi   = (ushort*)ws;                      ws += BLC * 2;
  ushort* oh_lo   = (ushort*)ws;                      ws += BLC * 2;
  ushort* owshi   = (ushort*)ws;                      ws += 2 * 512 * 512 * 2;
  ushort* owslo   = (ushort*)ws;                      ws += 2 * 512 * 512 * 2;

  // 1. window/offset projection + x hi/lo split (x read once)
  winoff_kernel<<<512, 256, 0, stream>>>(x, window_w, window_b, window_g,
                                         offset_w, offset_b, offset_g,
                                         halfwin, cenoff, xhi, xlo);
  // 0. weight hi/lo conversions
  split_bf16<<<256, 256, 0, stream>>>(kernel_w, wkvhi, wkvlo, 65536);
  split_bf16<<<256, 256, 0, stream>>>(v_w, wkvhi + 262144, wkvlo + 262144, 65536);

  // 2. kernel + v projections (fused dual MFMA GEMM over N=1024)
  gemm_mfma<0><<<512, 256, 0, stream>>>(xhi, xlo, wkvhi, wkvlo,
                                        kernel_b, v_b, kact, vbuf);
  // 3. fused rmsnorm+silu + deformable conv -> hi/lo bf16 output
  conv_row_kernel<<<8192, 512, 0, stream>>>(halfwin, cenoff, kact, kernel_g,
                                            vbuf, oh_hi, oh_lo);
  // 4. SE path
  colpart_kernel<<<64, 256, 0, stream>>>(oh_hi, partial);
  se_hid_kernel<<<64, 256, 0, stream>>>(partial, se_w1, hid_g);
  se_scale_kernel<<<256, 256, 0, stream>>>(hid_g, se_w2, scalebuf);
  // 5. fold SE scale into out_w (per batch), split to bf16
  scale_w_kernel<<<512, 256, 0, stream>>>(out_w, scalebuf, owshi, owslo);
  // 6. final MFMA GEMM + silu (A = conv output hi/lo, B = scaled out_w)
  gemm_mfma<1><<<256, 256, 0, stream>>>(oh_hi, oh_lo, owshi, owslo,
                                        nullptr, nullptr, out, nullptr);
}

// Round 6
// 122.362 us; speedup vs baseline: 2.5719x; 1.0276x over previous
//
#include <hip/hip_runtime.h>
#include <hip/hip_bf16.h>
#include <cstddef>
#include <cstdint>

// Problem constants (B=2, L=4096, C=512, H=8, K=64, D=64)
// max_window = 12, half_max = 6, S = 13, max_offset = 12.0, hid = 128

typedef _Float16 f16x8 __attribute__((ext_vector_type(8)));
typedef float f32x4 __attribute__((ext_vector_type(4)));

#define AS1 __attribute__((address_space(1)))
#define AS3 __attribute__((address_space(3)))

__device__ __forceinline__ void gload_lds16(const ushort* g, ushort* l) {
  __builtin_amdgcn_global_load_lds((const AS1 uint32_t*)g, (AS3 uint32_t*)l, 16, 0, 0);
}
__device__ __forceinline__ ushort f2h(float x) {
  _Float16 h = (_Float16)x;
  return __builtin_bit_cast(ushort, h);
}
__device__ __forceinline__ float h2f(ushort u) {
  return (float)__builtin_bit_cast(_Float16, u);
}
__device__ __forceinline__ float readlane_f(float v, int l) {
  return __int_as_float(__builtin_amdgcn_readlane(__float_as_int(v), l));
}

// ---------------------------------------------------------------------------
// fp32 -> fp16, vectorized float4 (weight tensors)
// ---------------------------------------------------------------------------
__global__ __launch_bounds__(256) void convert_h(
    const float* __restrict__ src, ushort* __restrict__ dst, int n4)
{
  for (int i = blockIdx.x * 256 + threadIdx.x; i < n4; i += gridDim.x * 256) {
    float4 v = ((const float4*)src)[i];
    ushort4 o = {f2h(v.x), f2h(v.y), f2h(v.z), f2h(v.w)};
    ((ushort4*)dst)[i] = o;
  }
}

// ---------------------------------------------------------------------------
// out_w * SE-scale -> per-batch fp16   ( w'[b][n][c] = w[n][c]*s[b][c] )
// ---------------------------------------------------------------------------
__global__ __launch_bounds__(256) void scale_w_kernel(
    const float* __restrict__ out_w, const float* __restrict__ scalebuf,
    ushort* __restrict__ dst)
{
  const int i = blockIdx.x * 256 + threadIdx.x;   // 131072 = 2 * 65536 float4
  const int b = i >> 16, iw = i & 65535, c4 = i & 127;
  float4 v = ((const float4*)out_w)[iw];
  float4 s = ((const float4*)scalebuf)[b * 128 + c4];
  ushort4 o = {f2h(v.x * s.x), f2h(v.y * s.y), f2h(v.z * s.z), f2h(v.w * s.w)};
  ((ushort4*)dst)[i] = o;
}

// ---------------------------------------------------------------------------
// fp16 MFMA GEMM: C[m,n] = sum_k A[m,k] * B[n,k]   (K=512)
// 128x128 tile, BK=64, 4 waves (2x2), 4x4 frags of 16x16x32, XOR-swizzled LDS
// (global source col-block pre-swizzled; LDS write linear; read XOR-matched).
// 1D grid + XCD-chunked swizzle.
// MODE 0: 512 blocks, N=1024 -> cols <512 to fp16 Ck (+bk), >=512 to Cv (+bv)
// MODE 1: 256 blocks, N=512, B per-batch offset -> silu -> fp32 Cf
// ---------------------------------------------------------------------------
template<int MODE>
__global__ __launch_bounds__(256, 2) void gemm_mfma(
    const ushort* __restrict__ A, const ushort* __restrict__ B,
    const float* __restrict__ bk, const float* __restrict__ bv,
    ushort* __restrict__ Ck, ushort* __restrict__ Cv,
    float* __restrict__ Cf)
{
  __shared__ ushort smem[2 * 8192];   // A tile 128x64 | B tile 128x64 (fp16)
  const int t = threadIdx.x, wid = t >> 6, l = t & 63;

  // XCD swizzle: bid%8 ~ XCD; each XCD owns an 8-tile bx stripe, all by.
  const int bid = blockIdx.x;
  const int xcd = bid & 7, idx = bid >> 3;
  const int bx = (xcd << 3) | (idx & 7);
  const int by = idx >> 3;
  const int m0 = bx * 128, n0 = by * 128;

  const ushort* Bp = B;
  if (MODE == 1) Bp += (size_t)(m0 >> 12) << 18;   // batch * 512*512

  // staging: 8 x gload16 per K-step; global col-block pre-swizzled by row&7
  const int swz = ((t & 7) ^ ((t >> 3) & 7)) * 8;
  const ushort* gsrc[8];
  uint32_t loff[8];
#pragma unroll
  for (int i = 0; i < 4; i++) {
    gsrc[i]     = A  + (size_t)(m0 + i * 32 + (t >> 3)) * 512 + swz;
    gsrc[4 + i] = Bp + (size_t)(n0 + i * 32 + (t >> 3)) * 512 + swz;
    loff[i]     = (i * 32 + wid * 8) * 64;           // wave-uniform
    loff[4 + i] = 8192 + (i * 32 + wid * 8) * 64;
  }

  f32x4 acc[4][4];
#pragma unroll
  for (int m = 0; m < 4; m++)
#pragma unroll
    for (int n = 0; n < 4; n++) acc[m][n] = (f32x4){0.f, 0.f, 0.f, 0.f};

  const int wr = wid >> 1, wc = wid & 1;
  const int fr = l & 15, fq = l >> 4;

  for (int k0 = 0; k0 < 512; k0 += 64) {
#pragma unroll
    for (int j = 0; j < 8; j++) {
      gload_lds16(gsrc[j], &smem[loff[j]]);
      gsrc[j] += 64;
    }
    __syncthreads();   // tiles resident

    f16x8 af[4][2], bf[4][2];
#pragma unroll
    for (int m = 0; m < 4; m++)
#pragma unroll
      for (int ks = 0; ks < 2; ks++) {
        const int ko = 8 * ((ks * 4 + fq) ^ (fr & 7));   // read-side XOR
        af[m][ks] = *(const f16x8*)&smem[(wr * 64 + m * 16 + fr) * 64 + ko];
        bf[m][ks] = *(const f16x8*)&smem[8192 + (wc * 64 + m * 16 + fr) * 64 + ko];
      }
#pragma unroll
    for (int ks = 0; ks < 2; ks++)
#pragma unroll
      for (int m = 0; m < 4; m++)
#pragma unroll
        for (int n = 0; n < 4; n++)
          acc[m][n] = __builtin_amdgcn_mfma_f32_16x16x32_f16(af[m][ks], bf[n][ks], acc[m][n], 0, 0, 0);
    __syncthreads();   // reads done before next stage overwrites
  }

  // epilogue: C/D layout col=lane&15, row=(lane>>4)*4+reg
  const int rbase = m0 + wr * 64 + (l >> 4) * 4;
  const int cbase = n0 + wc * 64 + (l & 15);
#pragma unroll
  for (int m = 0; m < 4; m++)
#pragma unroll
    for (int n = 0; n < 4; n++) {
      const int c = cbase + n * 16;
#pragma unroll
      for (int j = 0; j < 4; j++) {
        const int r = rbase + m * 16 + j;
        float v = acc[m][n][j];
        if (MODE == 0) {
          if (n0 < 512) Ck[(size_t)r * 512 + c]         = f2h(v + bk[c]);
          else          Cv[(size_t)r * 512 + (c - 512)] = f2h(v + bv[c - 512]);
        } else {
          Cf[(size_t)r * 512 + c] = v / (1.f + expf(-v));
        }
      }
    }
}

// ---------------------------------------------------------------------------
// window / offset projection (N=16 skinny) + rmsnorm(H=8) + sigmoid/tanh
// ALSO: writes the x fp16 copy (x already resident per row)
// ---------------------------------------------------------------------------
__global__ __launch_bounds__(256) void winoff_kernel(
    const float* __restrict__ x,
    const float* __restrict__ window_w, const float* __restrict__ window_b,
    const float* __restrict__ window_g,
    const float* __restrict__ offset_w, const float* __restrict__ offset_b,
    const float* __restrict__ offset_g,
    float* __restrict__ halfwin, float* __restrict__ cenoff,
    ushort* __restrict__ xh)
{
  __shared__ float wsm[16][512];   // rows 0..7 window_w, 8..15 offset_w
  const int t = threadIdx.x;
  {
    float4* dst = (float4*)&wsm[0][0];
    for (int i = t; i < 2048; i += 256)
      dst[i] = (i < 1024) ? ((const float4*)window_w)[i] : ((const float4*)offset_w)[i - 1024];
  }
  __syncthreads();
  const int wid = t >> 6, lane = t & 63;
  for (int it = 0; it < 4; it++) {
    const int row = blockIdx.x * 16 + it * 4 + wid;
    const float* xr = x + (size_t)row * 512;
    float xv[8];
#pragma unroll
    for (int j = 0; j < 8; j++) xv[j] = xr[lane + j * 64];
#pragma unroll
    for (int j = 0; j < 8; j++)
      xh[(size_t)row * 512 + lane + j * 64] = f2h(xv[j]);
    float s[16];
#pragma unroll
    for (int n = 0; n < 16; n++) {
      float p = 0.f;
#pragma unroll
      for (int j = 0; j < 8; j++) p += xv[j] * wsm[n][lane + j * 64];
#pragma unroll
      for (int off = 32; off >= 1; off >>= 1) p += __shfl_xor(p, off);
      s[n] = p;
    }
    float ssw = 0.f, sso = 0.f;
#pragma unroll
    for (int h = 0; h < 8; h++) {
      s[h]     += window_b[h]; ssw += s[h] * s[h];
      s[8 + h] += offset_b[h]; sso += s[8 + h] * s[8 + h];
    }
    float rw = rsqrtf(ssw * 0.125f + 1e-6f);
    float ro = rsqrtf(sso * 0.125f + 1e-6f);
    if (lane < 8) {
      float z  = window_g[lane] * s[lane] * rw;
      float wr2 = 1.f / (1.f + expf(-z));
      halfwin[(size_t)row * 8 + lane] = fmaxf((1.0f + wr2 * 11.0f) * 0.5f, 0.5f);
    } else if (lane < 16) {
      int h = lane - 8;
      float z = offset_g[h] * s[8 + h] * ro;
      cenoff[(size_t)row * 8 + h] = tanhf(z) * 12.0f;
    }
  }
}

// ---------------------------------------------------------------------------
// fused rmsnorm+silu + deformable conv: one block = one row (512 thr, 8 waves)
// wave w = head h, lane per d. frac(l+co+s) is constant in s, so the 13
// (v0,v1) bilinear pairs collapse to 14 consecutive rows with combined
// coefficients u_r: 14 loads instead of 26. XCD-chunked row swizzle.
// ---------------------------------------------------------------------------
__global__ __launch_bounds__(512) void conv_row_kernel(
    const float* __restrict__ halfwin, const float* __restrict__ cenoff,
    const ushort* __restrict__ kact_h, const float* __restrict__ kernel_g,
    const ushort* __restrict__ v_h, ushort* __restrict__ oh_h)
{
  __shared__ float kn[512];
  __shared__ float red[8];
  const int bid = blockIdx.x;                       // 8192
  const int row = ((bid & 7) << 10) | (bid >> 3);   // 1024 rows per XCD chunk
  const int t = threadIdx.x, w = t >> 6, lane = t & 63;
  const int b = row >> 12, l = row & 4095;

  // rmsnorm + silu on kact row (in LDS)
  float kraw = h2f(kact_h[(size_t)row * 512 + t]);
  float ss = kraw * kraw;
#pragma unroll
  for (int off = 32; off >= 1; off >>= 1) ss += __shfl_xor(ss, off);
  if (lane == 0) red[w] = ss;
  __syncthreads();
  float tot = red[0] + red[1] + red[2] + red[3]
            + red[4] + red[5] + red[6] + red[7];
  float r = rsqrtf(tot * (1.f / 512.f) + 1e-6f);
  float a = kernel_g[t] * kraw * r;
  kn[t] = a / (1.f + expf(-a));
  __syncthreads();

  const int gw = row * 8 + w;
  const float hw = halfwin[gw];
  const float co = cenoff[gw];
  const ushort* vbase = v_h + ((size_t)b * 4096) * 512 + w * 64;

  // weight phase: lane si in [0,13)
  float wgt = 0.f, frv = 0.f;
  int pfv = 0;
  if (lane < 13) {
    const int soff = lane - 6;
    float rel  = fabsf((float)soff) / hw;
    float ww   = __expf(-rel * rel);
    float npos = fminf(rel, 1.f) * 63.f;
    int   idx  = min((int)npos, 62);
    float wc   = npos - (float)idx;
    float kf = kn[w * 64 + idx], kc = kn[w * 64 + idx + 1];
    float kw = fmaxf(kf * (1.f - wc) + kc * wc, 0.f);
    float nb = (float)l + co + (float)soff;
    wgt = (nb >= 0.f && nb < 4096.f) ? (kw + 1.f) * ww : 0.f;
    float pc = fminf(fmaxf(nb, 0.f), 4094.999f);
    pfv = (int)pc;
    frv = pc - (float)pfv;
  }
  float wsum = wgt;
#pragma unroll
  for (int off = 32; off >= 1; off >>= 1) wsum += __shfl_xor(wsum, off);

  // combine bilinear weights onto the 14 distinct rows [base, base+13]
  const int base = __builtin_amdgcn_readlane(pfv, 0);
  float u = 0.f;
#pragma unroll
  for (int s = 0; s < 13; s++) {
    const float w_s  = readlane_f(wgt, s);
    const float fr_s = readlane_f(frv, s);
    const int   d    = __builtin_amdgcn_readlane(pfv, s) - base;  // 0..12
    if (lane == d)     u += w_s * (1.f - fr_s);
    if (lane == d + 1) u += w_s * fr_s;
  }

  float acc = 0.f;
#pragma unroll
  for (int rr = 0; rr < 14; rr++) {
    const float u_r = readlane_f(u, rr);
    if (u_r != 0.f) {                              // wave-uniform branch
      const int rowr = min(base + rr, 4095);
      acc = fmaf(u_r, h2f(vbase[(size_t)rowr * 512 + lane]), acc);
    }
  }

  float val = acc / fmaxf(wsum, 1.f);
  oh_h[(size_t)row * 512 + w * 64 + lane] = f2h(val);
}

// ---------------------------------------------------------------------------
// column partial sums over L chunks (for the SE mean), reads fp16
// ---------------------------------------------------------------------------
__global__ __launch_bounds__(256) void colpart_kernel(
    const ushort* __restrict__ oh_h, float* __restrict__ partial)
{
  const int blk = blockIdx.x;               // B*32
  const int b = blk >> 5, chunk = blk & 31;
  const int t = threadIdx.x;
  const size_t base = ((size_t)b * 4096 + (size_t)chunk * 128) * 512;
  float s0 = 0.f, s1 = 0.f;
  for (int i = 0; i < 128; i++) {
    const size_t o = base + (size_t)i * 512;
    s0 += h2f(oh_h[o + t]);
    s1 += h2f(oh_h[o + 256 + t]);
  }
  partial[(size_t)blk * 512 + t]       = s0;
  partial[(size_t)blk * 512 + 256 + t] = s1;
}

// ---------------------------------------------------------------------------
// SE stage 1+2 fused: mean inline, hid = silu(mean @ w1^T); wave per (b,j)
// ---------------------------------------------------------------------------
__global__ __launch_bounds__(256) void se_hid_kernel(
    const float* __restrict__ partial, const float* __restrict__ w1,
    float* __restrict__ hid_g)
{
  const int wid = threadIdx.x >> 6, lane = threadIdx.x & 63;
  const int g = blockIdx.x * 4 + wid;       // 0..255
  const int b2 = g >> 7, j = g & 127;
  float4 m0 = {0.f, 0.f, 0.f, 0.f}, m1 = {0.f, 0.f, 0.f, 0.f};
#pragma unroll 8
  for (int ch = 0; ch < 32; ch++) {
    const float4* pr = (const float4*)(partial + (size_t)(b2 * 32 + ch) * 512);
    float4 a0 = pr[lane * 2], a1 = pr[lane * 2 + 1];
    m0.x += a0.x; m0.y += a0.y; m0.z += a0.z; m0.w += a0.w;
    m1.x += a1.x; m1.y += a1.y; m1.z += a1.z; m1.w += a1.w;
  }
  float4 wv0 = ((const float4*)(w1 + (size_t)j * 512))[lane * 2];
  float4 wv1 = ((const float4*)(w1 + (size_t)j * 512))[lane * 2 + 1];
  float p = (wv0.x * m0.x + wv0.y * m0.y + wv0.z * m0.z + wv0.w * m0.w
           + wv1.x * m1.x + wv1.y * m1.y + wv1.z * m1.z + wv1.w * m1.w) * (1.f / 4096.f);
#pragma unroll
  for (int off = 32; off >= 1; off >>= 1) p += __shfl_xor(p, off);
  if (lane == 0) hid_g[g] = p / (1.f + expf(-p));
}

// ---------------------------------------------------------------------------
// SE stage 3: scale = sigmoid(hid @ w2^T)   wave per (b, c) output
// ---------------------------------------------------------------------------
__global__ __launch_bounds__(256) void se_scale_kernel(
    const float* __restrict__ hid_g, const float* __restrict__ w2,
    float* __restrict__ scalebuf)
{
  const int wid = threadIdx.x >> 6, lane = threadIdx.x & 63;
  const int g = blockIdx.x * 4 + wid;       // 0..1023
  const int b3 = g >> 9, c = g & 511;
  float2 wv = ((const float2*)(w2 + (size_t)c * 128))[lane];
  float2 hv = ((const float2*)(hid_g + b3 * 128))[lane];
  float p = wv.x * hv.x + wv.y * hv.y;
#pragma unroll
  for (int off = 32; off >= 1; off >>= 1) p += __shfl_xor(p, off);
  if (lane == 0) scalebuf[g] = 1.f / (1.f + expf(-p));
}

// ---------------------------------------------------------------------------
extern "C" void kernel_launch(void* const* d_in, const int* in_sizes, int n_in,
                              void* d_out, int out_size, void* d_ws, size_t ws_size,
                              hipStream_t stream) {
  const float* x        = (const float*)d_in[0];
  const float* window_w = (const float*)d_in[1];
  const float* window_b = (const float*)d_in[2];
  const float* window_g = (const float*)d_in[3];
  const float* offset_w = (const float*)d_in[4];
  const float* offset_b = (const float*)d_in[5];
  const float* offset_g = (const float*)d_in[6];
  const float* kernel_w = (const float*)d_in[7];
  const float* kernel_b = (const float*)d_in[8];
  const float* kernel_g = (const float*)d_in[9];
  const float* v_w      = (const float*)d_in[10];
  const float* v_b      = (const float*)d_in[11];
  const float* se_w1    = (const float*)d_in[12];
  const float* se_w2    = (const float*)d_in[13];
  const float* out_w    = (const float*)d_in[14];
  float* out = (float*)d_out;
  char* ws   = (char*)d_ws;

  const size_t BLC = (size_t)8192 * 512;
  float* halfwin  = (float*)ws;                       ws += 65536 * 4;
  float* cenoff   = (float*)ws;                       ws += 65536 * 4;
  float* partial  = (float*)ws;                       ws += 64 * 512 * 4;
  float* hid_g    = (float*)ws;                       ws += 256 * 4;
  float* scalebuf = (float*)ws;                       ws += 1024 * 4;
  ushort* xh      = (ushort*)ws;                      ws += BLC * 2;
  ushort* wkv_h   = (ushort*)ws;                      ws += 1024 * 512 * 2;
  ushort* kact_h  = (ushort*)ws;                      ws += BLC * 2;
  ushort* v_h     = (ushort*)ws;                      ws += BLC * 2;
  ushort* oh_h    = (ushort*)ws;                      ws += BLC * 2;
  ushort* ow_h    = (ushort*)ws;                      ws += 2 * 512 * 512 * 2;

  // 1. window/offset projection + x fp16 copy (x read once)
  winoff_kernel<<<512, 256, 0, stream>>>(x, window_w, window_b, window_g,
                                         offset_w, offset_b, offset_g,
                                         halfwin, cenoff, xh);
  // 0. weight fp16 conversions
  convert_h<<<256, 256, 0, stream>>>(kernel_w, wkv_h, 65536);
  convert_h<<<256, 256, 0, stream>>>(v_w, wkv_h + 262144, 65536);

  // 2. kernel + v projections (fused dual fp16 MFMA GEMM over N=1024)
  gemm_mfma<0><<<512, 256, 0, stream>>>(xh, wkv_h, kernel_b, v_b,
                                        kact_h, v_h, nullptr);
  // 3. fused rmsnorm+silu + deformable conv (14-row combined gather)
  conv_row_kernel<<<8192, 512, 0, stream>>>(halfwin, cenoff, kact_h, kernel_g,
                                            v_h, oh_h);
  // 4. SE path
  colpart_kernel<<<64, 256, 0, stream>>>(oh_h, partial);
  se_hid_kernel<<<64, 256, 0, stream>>>(partial, se_w1, hid_g);
  se_scale_kernel<<<256, 256, 0, stream>>>(hid_g, se_w2, scalebuf);
  // 5. fold SE scale into out_w (per batch), fp16
  scale_w_kernel<<<512, 256, 0, stream>>>(out_w, scalebuf, ow_h);
  // 6. final fp16 MFMA GEMM + silu
  gemm_mfma<1><<<256, 256, 0, stream>>>(oh_h, ow_h, nullptr, nullptr,
                                        nullptr, nullptr, out);
}

// Round 7
// 91.234 us; speedup vs baseline: 3.4494x; 1.3412x over previous
//
#include <hip/hip_runtime.h>
#include <hip/hip_bf16.h>
#include <cstddef>
#include <cstdint>

// Problem constants (B=2, L=4096, C=512, H=8, K=64, D=64)
// max_window = 12, half_max = 6, S = 13, max_offset = 12.0, hid = 128

typedef _Float16 f16x8 __attribute__((ext_vector_type(8)));
typedef float f32x4 __attribute__((ext_vector_type(4)));

#define AS1 __attribute__((address_space(1)))
#define AS3 __attribute__((address_space(3)))

__device__ __forceinline__ void gload_lds16(const ushort* g, ushort* l) {
  __builtin_amdgcn_global_load_lds((const AS1 uint32_t*)g, (AS3 uint32_t*)l, 16, 0, 0);
}
__device__ __forceinline__ ushort f2h(float x) {
  _Float16 h = (_Float16)x;
  return __builtin_bit_cast(ushort, h);
}
__device__ __forceinline__ float h2f(ushort u) {
  return (float)__builtin_bit_cast(_Float16, u);
}
__device__ __forceinline__ float readlane_f(float v, int l) {
  return __int_as_float(__builtin_amdgcn_readlane(__float_as_int(v), l));
}

// ---------------------------------------------------------------------------
// fp32 -> fp16, vectorized float4 (weight tensors)
// ---------------------------------------------------------------------------
__global__ __launch_bounds__(256) void convert_h(
    const float* __restrict__ src, ushort* __restrict__ dst, int n4)
{
  for (int i = blockIdx.x * 256 + threadIdx.x; i < n4; i += gridDim.x * 256) {
    float4 v = ((const float4*)src)[i];
    ushort4 o = {f2h(v.x), f2h(v.y), f2h(v.z), f2h(v.w)};
    ((ushort4*)dst)[i] = o;
  }
}

// ---------------------------------------------------------------------------
// out_w * SE-scale -> per-batch fp16   ( w'[b][n][c] = w[n][c]*s[b][c] )
// ---------------------------------------------------------------------------
__global__ __launch_bounds__(256) void scale_w_kernel(
    const float* __restrict__ out_w, const float* __restrict__ scalebuf,
    ushort* __restrict__ dst)
{
  const int i = blockIdx.x * 256 + threadIdx.x;   // 131072 = 2 * 65536 float4
  const int b = i >> 16, iw = i & 65535, c4 = i & 127;
  float4 v = ((const float4*)out_w)[iw];
  float4 s = ((const float4*)scalebuf)[b * 128 + c4];
  ushort4 o = {f2h(v.x * s.x), f2h(v.y * s.y), f2h(v.z * s.z), f2h(v.w * s.w)};
  ((ushort4*)dst)[i] = o;
}

// ---------------------------------------------------------------------------
// fp16 MFMA GEMM: C[m,n] = sum_k A[m,k] * B[n,k]   (K=512)
// 128x128 tile, BK=64, 4 waves (2x2), 4x4 frags of 16x16x32, XOR-swizzled LDS
// (global source col-block pre-swizzled; LDS write linear; read XOR-matched).
// 1D grid + XCD-chunked swizzle.
// MODE 0: 512 blocks, N=1024 -> cols <512 to fp16 Ck (+bk), >=512 to Cv (+bv)
// MODE 1: 256 blocks, N=512, B per-batch offset -> silu -> fp32 Cf
// ---------------------------------------------------------------------------
template<int MODE>
__global__ __launch_bounds__(256, 2) void gemm_mfma(
    const ushort* __restrict__ A, const ushort* __restrict__ B,
    const float* __restrict__ bk, const float* __restrict__ bv,
    ushort* __restrict__ Ck, ushort* __restrict__ Cv,
    float* __restrict__ Cf)
{
  __shared__ ushort smem[2 * 8192];   // A tile 128x64 | B tile 128x64 (fp16)
  const int t = threadIdx.x, wid = t >> 6, l = t & 63;

  // XCD swizzle: bid%8 ~ XCD; each XCD owns an 8-tile bx stripe, all by.
  const int bid = blockIdx.x;
  const int xcd = bid & 7, idx = bid >> 3;
  const int bx = (xcd << 3) | (idx & 7);
  const int by = idx >> 3;
  const int m0 = bx * 128, n0 = by * 128;

  const ushort* Bp = B;
  if (MODE == 1) Bp += (size_t)(m0 >> 12) << 18;   // batch * 512*512

  // staging: 8 x gload16 per K-step; global col-block pre-swizzled by row&7
  const int swz = ((t & 7) ^ ((t >> 3) & 7)) * 8;
  const ushort* gsrc[8];
  uint32_t loff[8];
#pragma unroll
  for (int i = 0; i < 4; i++) {
    gsrc[i]     = A  + (size_t)(m0 + i * 32 + (t >> 3)) * 512 + swz;
    gsrc[4 + i] = Bp + (size_t)(n0 + i * 32 + (t >> 3)) * 512 + swz;
    loff[i]     = (i * 32 + wid * 8) * 64;           // wave-uniform
    loff[4 + i] = 8192 + (i * 32 + wid * 8) * 64;
  }

  f32x4 acc[4][4];
#pragma unroll
  for (int m = 0; m < 4; m++)
#pragma unroll
    for (int n = 0; n < 4; n++) acc[m][n] = (f32x4){0.f, 0.f, 0.f, 0.f};

  const int wr = wid >> 1, wc = wid & 1;
  const int fr = l & 15, fq = l >> 4;

  for (int k0 = 0; k0 < 512; k0 += 64) {
#pragma unroll
    for (int j = 0; j < 8; j++) {
      gload_lds16(gsrc[j], &smem[loff[j]]);
      gsrc[j] += 64;
    }
    __syncthreads();   // tiles resident

    f16x8 af[4][2], bf[4][2];
#pragma unroll
    for (int m = 0; m < 4; m++)
#pragma unroll
      for (int ks = 0; ks < 2; ks++) {
        const int ko = 8 * ((ks * 4 + fq) ^ (fr & 7));   // read-side XOR
        af[m][ks] = *(const f16x8*)&smem[(wr * 64 + m * 16 + fr) * 64 + ko];
        bf[m][ks] = *(const f16x8*)&smem[8192 + (wc * 64 + m * 16 + fr) * 64 + ko];
      }
#pragma unroll
    for (int ks = 0; ks < 2; ks++)
#pragma unroll
      for (int m = 0; m < 4; m++)
#pragma unroll
        for (int n = 0; n < 4; n++)
          acc[m][n] = __builtin_amdgcn_mfma_f32_16x16x32_f16(af[m][ks], bf[n][ks], acc[m][n], 0, 0, 0);
    __syncthreads();   // reads done before next stage overwrites
  }

  // epilogue: C/D layout col=lane&15, row=(lane>>4)*4+reg
  const int rbase = m0 + wr * 64 + (l >> 4) * 4;
  const int cbase = n0 + wc * 64 + (l & 15);
#pragma unroll
  for (int m = 0; m < 4; m++)
#pragma unroll
    for (int n = 0; n < 4; n++) {
      const int c = cbase + n * 16;
#pragma unroll
      for (int j = 0; j < 4; j++) {
        const int r = rbase + m * 16 + j;
        float v = acc[m][n][j];
        if (MODE == 0) {
          if (n0 < 512) Ck[(size_t)r * 512 + c]         = f2h(v + bk[c]);
          else          Cv[(size_t)r * 512 + (c - 512)] = f2h(v + bv[c - 512]);
        } else {
          Cf[(size_t)r * 512 + c] = v / (1.f + expf(-v));
        }
      }
    }
}

// ---------------------------------------------------------------------------
// window / offset projection (N=16 skinny) + rmsnorm(H=8) + sigmoid/tanh
// ALSO: writes the x fp16 copy (x already resident per row)
// ---------------------------------------------------------------------------
__global__ __launch_bounds__(256) void winoff_kernel(
    const float* __restrict__ x,
    const float* __restrict__ window_w, const float* __restrict__ window_b,
    const float* __restrict__ window_g,
    const float* __restrict__ offset_w, const float* __restrict__ offset_b,
    const float* __restrict__ offset_g,
    float* __restrict__ halfwin, float* __restrict__ cenoff,
    ushort* __restrict__ xh)
{
  __shared__ float wsm[16][512];   // rows 0..7 window_w, 8..15 offset_w
  const int t = threadIdx.x;
  {
    float4* dst = (float4*)&wsm[0][0];
    for (int i = t; i < 2048; i += 256)
      dst[i] = (i < 1024) ? ((const float4*)window_w)[i] : ((const float4*)offset_w)[i - 1024];
  }
  __syncthreads();
  const int wid = t >> 6, lane = t & 63;
  for (int it = 0; it < 4; it++) {
    const int row = blockIdx.x * 16 + it * 4 + wid;
    const float* xr = x + (size_t)row * 512;
    float xv[8];
#pragma unroll
    for (int j = 0; j < 8; j++) xv[j] = xr[lane + j * 64];
#pragma unroll
    for (int j = 0; j < 8; j++)
      xh[(size_t)row * 512 + lane + j * 64] = f2h(xv[j]);
    float s[16];
#pragma unroll
    for (int n = 0; n < 16; n++) {
      float p = 0.f;
#pragma unroll
      for (int j = 0; j < 8; j++) p += xv[j] * wsm[n][lane + j * 64];
#pragma unroll
      for (int off = 32; off >= 1; off >>= 1) p += __shfl_xor(p, off);
      s[n] = p;
    }
    float ssw = 0.f, sso = 0.f;
#pragma unroll
    for (int h = 0; h < 8; h++) {
      s[h]     += window_b[h]; ssw += s[h] * s[h];
      s[8 + h] += offset_b[h]; sso += s[8 + h] * s[8 + h];
    }
    float rw = rsqrtf(ssw * 0.125f + 1e-6f);
    float ro = rsqrtf(sso * 0.125f + 1e-6f);
    if (lane < 8) {
      float z  = window_g[lane] * s[lane] * rw;
      float wr2 = 1.f / (1.f + expf(-z));
      halfwin[(size_t)row * 8 + lane] = fmaxf((1.0f + wr2 * 11.0f) * 0.5f, 0.5f);
    } else if (lane < 16) {
      int h = lane - 8;
      float z = offset_g[h] * s[8 + h] * ro;
      cenoff[(size_t)row * 8 + h] = tanhf(z) * 12.0f;
    }
  }
}

// ---------------------------------------------------------------------------
// fused rmsnorm+silu + deformable conv: one block = one row (512 thr, 8 waves)
// wave w = head h, lane per d. Interior rows (all but ~40/batch): pf_s = base+s
// exactly, so bilinear collapse = one shfl_up and the 14 gather loads are
// UNCONDITIONAL (batch-issued). Edge rows take the general per-s path.
// ---------------------------------------------------------------------------
__global__ __launch_bounds__(512) void conv_row_kernel(
    const float* __restrict__ halfwin, const float* __restrict__ cenoff,
    const ushort* __restrict__ kact_h, const float* __restrict__ kernel_g,
    const ushort* __restrict__ v_h, ushort* __restrict__ oh_h)
{
  __shared__ float kn[512];
  __shared__ float red[8];
  const int bid = blockIdx.x;                       // 8192
  const int row = ((bid & 7) << 10) | (bid >> 3);   // 1024 rows per XCD chunk
  const int t = threadIdx.x, w = t >> 6, lane = t & 63;
  const int b = row >> 12, l = row & 4095;

  // rmsnorm + silu on kact row (in LDS)
  float kraw = h2f(kact_h[(size_t)row * 512 + t]);
  float ss = kraw * kraw;
#pragma unroll
  for (int off = 32; off >= 1; off >>= 1) ss += __shfl_xor(ss, off);
  if (lane == 0) red[w] = ss;
  __syncthreads();
  float tot = red[0] + red[1] + red[2] + red[3]
            + red[4] + red[5] + red[6] + red[7];
  float r = rsqrtf(tot * (1.f / 512.f) + 1e-6f);
  float a = kernel_g[t] * kraw * r;
  kn[t] = a / (1.f + __expf(-a));
  __syncthreads();

  const int gw = row * 8 + w;
  const float hw = halfwin[gw];
  const float co = cenoff[gw];
  const ushort* vbase = v_h + ((size_t)b * 4096) * 512 + w * 64 + lane;

  // weight phase: lane si in [0,13)
  float wgt = 0.f, frv = 0.f;
  int pfv = 0;
  if (lane < 13) {
    const int soff = lane - 6;
    float rel  = fabsf((float)soff) / hw;
    float ww   = __expf(-rel * rel);
    float npos = fminf(rel, 1.f) * 63.f;
    int   idx  = min((int)npos, 62);
    float wc   = npos - (float)idx;
    float kf = kn[w * 64 + idx], kc = kn[w * 64 + idx + 1];
    float kw = fmaxf(kf * (1.f - wc) + kc * wc, 0.f);
    float nb = (float)l + co + (float)soff;
    wgt = (nb >= 0.f && nb < 4096.f) ? (kw + 1.f) * ww : 0.f;
    float pc = fminf(fmaxf(nb, 0.f), 4094.999f);
    pfv = (int)pc;
    frv = pc - (float)pfv;
  }
  float wsum = wgt;
#pragma unroll
  for (int off = 32; off >= 1; off >>= 1) wsum += __shfl_xor(wsum, off);

  const int base = __builtin_amdgcn_readlane(pfv, 0);
  const bool ok = (lane >= 13) || (pfv == base + lane);
  const bool fast = __all((int)ok) && (base + 13 <= 4095);

  float acc = 0.f;
  if (fast) {
    // collapse bilinear: u[r] = w_r*(1-fr_r) + w_{r-1}*fr_{r-1}
    float wfr = wgt * frv;
    float w1f = wgt - wfr;
    float up  = __shfl_up(wfr, 1);
    float u = (lane < 13 ? w1f : 0.f) + ((lane >= 1 && lane <= 13) ? up : 0.f);
    const ushort* vr = vbase + (size_t)base * 512;
    float xv[14];
#pragma unroll
    for (int rr = 0; rr < 14; rr++) xv[rr] = h2f(vr[(size_t)rr * 512]);
#pragma unroll
    for (int rr = 0; rr < 14; rr++) acc = fmaf(readlane_f(u, rr), xv[rr], acc);
  } else {
    // general path (sequence edges only)
#pragma unroll
    for (int si = 0; si < 13; si++) {
      const float w_s  = readlane_f(wgt, si);
      const float fr_s = readlane_f(frv, si);
      const int   pf_s = __builtin_amdgcn_readlane(pfv, si);
      const int   pcl  = min(pf_s + 1, 4095);
      float v0 = h2f(vbase[(size_t)pf_s * 512]);
      float v1 = h2f(vbase[(size_t)pcl * 512]);
      float t0 = v0 + fr_s * (v1 - v0);
      acc = fmaf(w_s, t0, acc);
    }
  }

  float val = acc / fmaxf(wsum, 1.f);
  oh_h[(size_t)row * 512 + w * 64 + lane] = f2h(val);
}

// ---------------------------------------------------------------------------
// column partial sums over 64-row chunks (for the SE mean), uint (2-col) loads
// ---------------------------------------------------------------------------
__global__ __launch_bounds__(256) void colpart_kernel(
    const ushort* __restrict__ oh_h, float* __restrict__ partial)
{
  const int blk = blockIdx.x;               // B*64 = 128
  const int b = blk >> 6, chunk = blk & 63;
  const int t = threadIdx.x;                // cols 2t, 2t+1
  const size_t base = ((size_t)b * 4096 + (size_t)chunk * 64) * 512;
  float s0 = 0.f, s1 = 0.f;
  for (int i = 0; i < 64; i++) {
    uint u = *(const uint*)(oh_h + base + (size_t)i * 512 + t * 2);
    s0 += h2f((ushort)(u & 0xffffu));
    s1 += h2f((ushort)(u >> 16));
  }
  partial[(size_t)blk * 512 + t * 2]     = s0;
  partial[(size_t)blk * 512 + t * 2 + 1] = s1;
}

// ---------------------------------------------------------------------------
// SE stage 1+2 fused: mean inline, hid = silu(mean @ w1^T); wave per (b,j)
// ---------------------------------------------------------------------------
__global__ __launch_bounds__(256) void se_hid_kernel(
    const float* __restrict__ partial, const float* __restrict__ w1,
    float* __restrict__ hid_g)
{
  const int wid = threadIdx.x >> 6, lane = threadIdx.x & 63;
  const int g = blockIdx.x * 4 + wid;       // 0..255
  const int b2 = g >> 7, j = g & 127;
  float4 m0 = {0.f, 0.f, 0.f, 0.f}, m1 = {0.f, 0.f, 0.f, 0.f};
#pragma unroll 8
  for (int ch = 0; ch < 64; ch++) {
    const float4* pr = (const float4*)(partial + (size_t)(b2 * 64 + ch) * 512);
    float4 a0 = pr[lane * 2], a1 = pr[lane * 2 + 1];
    m0.x += a0.x; m0.y += a0.y; m0.z += a0.z; m0.w += a0.w;
    m1.x += a1.x; m1.y += a1.y; m1.z += a1.z; m1.w += a1.w;
  }
  float4 wv0 = ((const float4*)(w1 + (size_t)j * 512))[lane * 2];
  float4 wv1 = ((const float4*)(w1 + (size_t)j * 512))[lane * 2 + 1];
  float p = (wv0.x * m0.x + wv0.y * m0.y + wv0.z * m0.z + wv0.w * m0.w
           + wv1.x * m1.x + wv1.y * m1.y + wv1.z * m1.z + wv1.w * m1.w) * (1.f / 4096.f);
#pragma unroll
  for (int off = 32; off >= 1; off >>= 1) p += __shfl_xor(p, off);
  if (lane == 0) hid_g[g] = p / (1.f + expf(-p));
}

// ---------------------------------------------------------------------------
// SE stage 3: scale = sigmoid(hid @ w2^T)   wave per (b, c) output
// ---------------------------------------------------------------------------
__global__ __launch_bounds__(256) void se_scale_kernel(
    const float* __restrict__ hid_g, const float* __restrict__ w2,
    float* __restrict__ scalebuf)
{
  const int wid = threadIdx.x >> 6, lane = threadIdx.x & 63;
  const int g = blockIdx.x * 4 + wid;       // 0..1023
  const int b3 = g >> 9, c = g & 511;
  float2 wv = ((const float2*)(w2 + (size_t)c * 128))[lane];
  float2 hv = ((const float2*)(hid_g + b3 * 128))[lane];
  float p = wv.x * hv.x + wv.y * hv.y;
#pragma unroll
  for (int off = 32; off >= 1; off >>= 1) p += __shfl_xor(p, off);
  if (lane == 0) scalebuf[g] = 1.f / (1.f + expf(-p));
}

// ---------------------------------------------------------------------------
extern "C" void kernel_launch(void* const* d_in, const int* in_sizes, int n_in,
                              void* d_out, int out_size, void* d_ws, size_t ws_size,
                              hipStream_t stream) {
  const float* x        = (const float*)d_in[0];
  const float* window_w = (const float*)d_in[1];
  const float* window_b = (const float*)d_in[2];
  const float* window_g = (const float*)d_in[3];
  const float* offset_w = (const float*)d_in[4];
  const float* offset_b = (const float*)d_in[5];
  const float* offset_g = (const float*)d_in[6];
  const float* kernel_w = (const float*)d_in[7];
  const float* kernel_b = (const float*)d_in[8];
  const float* kernel_g = (const float*)d_in[9];
  const float* v_w      = (const float*)d_in[10];
  const float* v_b      = (const float*)d_in[11];
  const float* se_w1    = (const float*)d_in[12];
  const float* se_w2    = (const float*)d_in[13];
  const float* out_w    = (const float*)d_in[14];
  float* out = (float*)d_out;
  char* ws   = (char*)d_ws;

  const size_t BLC = (size_t)8192 * 512;
  float* halfwin  = (float*)ws;                       ws += 65536 * 4;
  float* cenoff   = (float*)ws;                       ws += 65536 * 4;
  float* partial  = (float*)ws;                       ws += 128 * 512 * 4;
  float* hid_g    = (float*)ws;                       ws += 256 * 4;
  float* scalebuf = (float*)ws;                       ws += 1024 * 4;
  ushort* xh      = (ushort*)ws;                      ws += BLC * 2;
  ushort* wkv_h   = (ushort*)ws;                      ws += 1024 * 512 * 2;
  ushort* kact_h  = (ushort*)ws;                      ws += BLC * 2;
  ushort* v_h     = (ushort*)ws;                      ws += BLC * 2;
  ushort* oh_h    = (ushort*)ws;                      ws += BLC * 2;
  ushort* ow_h    = (ushort*)ws;                      ws += 2 * 512 * 512 * 2;

  // 1. window/offset projection + x fp16 copy (x read once)
  winoff_kernel<<<512, 256, 0, stream>>>(x, window_w, window_b, window_g,
                                         offset_w, offset_b, offset_g,
                                         halfwin, cenoff, xh);
  // 0. weight fp16 conversions
  convert_h<<<256, 256, 0, stream>>>(kernel_w, wkv_h, 65536);
  convert_h<<<256, 256, 0, stream>>>(v_w, wkv_h + 262144, 65536);

  // 2. kernel + v projections (fused dual fp16 MFMA GEMM over N=1024)
  gemm_mfma<0><<<512, 256, 0, stream>>>(xh, wkv_h, kernel_b, v_b,
                                        kact_h, v_h, nullptr);
  // 3. fused rmsnorm+silu + deformable conv (branch-free interior gather)
  conv_row_kernel<<<8192, 512, 0, stream>>>(halfwin, cenoff, kact_h, kernel_g,
                                            v_h, oh_h);
  // 4. SE path
  colpart_kernel<<<128, 256, 0, stream>>>(oh_h, partial);
  se_hid_kernel<<<64, 256, 0, stream>>>(partial, se_w1, hid_g);
  se_scale_kernel<<<256, 256, 0, stream>>>(hid_g, se_w2, scalebuf);
  // 5. fold SE scale into out_w (per batch), fp16
  scale_w_kernel<<<512, 256, 0, stream>>>(out_w, scalebuf, ow_h);
  // 6. final fp16 MFMA GEMM + silu
  gemm_mfma<1><<<256, 256, 0, stream>>>(oh_h, ow_h, nullptr, nullptr,
                                        nullptr, nullptr, out);
}